// Round 1
// baseline (1437.338 us; speedup 1.0000x reference)
//
#include <hip/hip_runtime.h>

#define NPNT 4096
#define NSTK 32

// ---------------- workspace layout (floats) ----------------
static const size_t OFF_XT   = 0;          // 4*4096*256 = 4194304 (aliased by E later: 4*1024*768)
static const size_t OFF_P    = 4194304;    // 4194304
static const size_t OFF_Q    = 8388608;    // 4194304
static const size_t OFF_SQD  = 12582912;   // 16384
static const size_t OFF_SPFD = 12599296;   // 16384
static const size_t OFF_XS   = 12615680;   // 32768
static const size_t OFF_PS   = 12648448;   // 32768
static const size_t OFF_QS   = 12681216;   // 32768
static const size_t OFF_SUP  = 12713984;   // 32768
static const size_t OFF_PDL  = 12746752;   // 327680
static const size_t OFF_PIL  = 13074432;   // 327680 (int)
static const size_t OFF_KNN  = 13402112;   // 163840 (int)
static const size_t OFF_IDXS = 13565952;   // 256 (int)
static const size_t OFF_FPS  = 13566208;   // 64 (int)

__device__ __forceinline__ bool lexlt(float d1, int i1, float d2, int i2) {
  return (d1 < d2) || (d1 == d2 && i1 < i2);
}
__device__ __forceinline__ void insert10(float ld[10], int li[10], float d, int i) {
  if (!lexlt(d, i, ld[9], li[9])) return;
  ld[9] = d; li[9] = i;
#pragma unroll
  for (int j = 9; j > 0; j--) {
    if (lexlt(ld[j], li[j], ld[j-1], li[j-1])) {
      float td = ld[j]; ld[j] = ld[j-1]; ld[j-1] = td;
      int ti = li[j]; li[j] = li[j-1]; li[j-1] = ti;
    }
  }
}

// ---------------- K0a: Xt dense half (transpose dense_fea [b,c,n] -> Xt[b,n,c]) ----------------
__global__ __launch_bounds__(256) void k_build_xt_dense(const float* __restrict__ df, float* __restrict__ xt) {
  // grid (4, 64, 4): b, ntile(64), ctile(32)
  int b = blockIdx.x, n0 = blockIdx.y * 64, c0 = blockIdx.z * 32;
  __shared__ float T[32][68];
  int t = threadIdx.x;
  {
    int cl = t >> 3, seg = t & 7;
#pragma unroll
    for (int r = 0; r < 2; r++) {
      int f4 = seg * 2 + r;
      float4 v = *(const float4*)&df[((size_t)b * 128 + c0 + cl) * NPNT + n0 + f4 * 4];
      *(float4*)&T[cl][f4 * 4] = v;
    }
  }
  __syncthreads();
  {
    int nl = t >> 2, q = t & 3;
    float4 v0, v1;
    v0.x = T[q*8+0][nl]; v0.y = T[q*8+1][nl]; v0.z = T[q*8+2][nl]; v0.w = T[q*8+3][nl];
    v1.x = T[q*8+4][nl]; v1.y = T[q*8+5][nl]; v1.z = T[q*8+6][nl]; v1.w = T[q*8+7][nl];
    float* dst = &xt[((size_t)b * NPNT + n0 + nl) * 256 + c0 + q * 8];
    *(float4*)dst = v0; *(float4*)(dst + 4) = v1;
  }
}

// ---------------- K0b: Xt sparse half (broadcast sparse_fea onto points) ----------------
__global__ __launch_bounds__(256) void k_build_xt_sparse(const float* __restrict__ sf, float* __restrict__ xt) {
  int tid = blockIdx.x * 256 + threadIdx.x;   // 2048 blocks: 4*4096*32 f4 units
  int b = tid >> 17;
  int rem = tid & 131071;
  int n = rem >> 5, q = rem & 31;
  int s = n >> 7;
  float4 v;
  v.x = sf[((size_t)b * 128 + q*4+0) * NSTK + s];
  v.y = sf[((size_t)b * 128 + q*4+1) * NSTK + s];
  v.z = sf[((size_t)b * 128 + q*4+2) * NSTK + s];
  v.w = sf[((size_t)b * 128 + q*4+3) * NSTK + s];
  *(float4*)&xt[((size_t)b * NPNT + n) * 256 + 128 + q * 4] = v;
}

// ---------------- K0c: sqd[b*4096+n] = sum_c Xt^2 ----------------
__global__ __launch_bounds__(256) void k_sqd(const float* __restrict__ xt, float* __restrict__ sqd) {
  int row = blockIdx.x * 4 + (threadIdx.x >> 6);
  int lane = threadIdx.x & 63;
  float4 v = *(const float4*)&xt[(size_t)row * 256 + lane * 4];
  float s = v.x * v.x;
  s += v.y * v.y; s += v.z * v.z; s += v.w * v.w;
#pragma unroll
  for (int off = 32; off; off >>= 1) s += __shfl_down(s, off, 64);
  if (lane == 0) sqd[row] = s;
}

// ---------------- K1: DenseToSparse conv(1,3)+BN+ReLU+max over points ----------------
__global__ __launch_bounds__(256) void k_d2s(const float* __restrict__ df, const float* __restrict__ w,
    const float* __restrict__ cb, const float* __restrict__ g, const float* __restrict__ bt,
    float* __restrict__ spfd) {
  // grid (4, 2, 64): b, otile(64), ntile(64)
  int b = blockIdx.x, o0 = blockIdx.y * 64, n0 = blockIdx.z * 64;
  int t = threadIdx.x;
  __shared__ float A[96][64];   // [iloc*3+kw][o]
  __shared__ float Bs[32][68];  // [iloc][n halo]
  float acc[4][4];
#pragma unroll
  for (int i = 0; i < 4; i++)
#pragma unroll
    for (int j = 0; j < 4; j++) acc[i][j] = 0.0f;
  int tn = t & 15, to = t >> 4;
  for (int ic = 0; ic < 128; ic += 32) {
    {
      int ol = t >> 2, q = t & 3;
      const float* src = &w[((size_t)(o0 + ol) * 128 + ic) * 3 + q * 24];
#pragma unroll
      for (int r = 0; r < 6; r++) {
        float4 v = *(const float4*)&src[r * 4];
        int e = q * 24 + r * 4;
        A[e+0][ol] = v.x; A[e+1][ol] = v.y; A[e+2][ol] = v.z; A[e+3][ol] = v.w;
      }
    }
    for (int idx = t; idx < 32 * 17; idx += 256) {
      int row = idx / 17, f4 = idx % 17;
      int nb = n0 + f4 * 4;
      const float* srow = &df[((size_t)b * 128 + ic + row) * NPNT];
      float4 v;
      if (nb + 3 < NPNT) v = *(const float4*)&srow[nb];
      else {
        v.x = srow[nb   < NPNT ? nb   : NPNT-1];
        v.y = srow[nb+1 < NPNT ? nb+1 : NPNT-1];
        v.z = srow[nb+2 < NPNT ? nb+2 : NPNT-1];
        v.w = srow[nb+3 < NPNT ? nb+3 : NPNT-1];
      }
      *(float4*)&Bs[row][f4 * 4] = v;
    }
    __syncthreads();
#pragma unroll 2
    for (int ii = 0; ii < 32; ii++) {
      float bv[8];
      *(float4*)&bv[0] = *(const float4*)&Bs[ii][tn * 4];
      *(float4*)&bv[4] = *(const float4*)&Bs[ii][tn * 4 + 4];
#pragma unroll
      for (int kw = 0; kw < 3; kw++) {
        float4 av = *(const float4*)&A[ii * 3 + kw][to * 4];
#pragma unroll
        for (int j = 0; j < 4; j++) {
          float bvj = bv[kw + j];
          acc[0][j] = fmaf(av.x, bvj, acc[0][j]);
          acc[1][j] = fmaf(av.y, bvj, acc[1][j]);
          acc[2][j] = fmaf(av.z, bvj, acc[2][j]);
          acc[3][j] = fmaf(av.w, bvj, acc[3][j]);
        }
      }
    }
    __syncthreads();
  }
  int s = n0 >> 7;
#pragma unroll
  for (int i = 0; i < 4; i++) {
    int o = o0 + to * 4 + i;
    float gg = g[o], bb = cb[o], bo = bt[o];
    float m = 0.0f;
#pragma unroll
    for (int j = 0; j < 4; j++) {
      int n = n0 + tn * 4 + j;
      int p = n & 127;
      if (p < 126) {
        float v = fmaf(gg, acc[i][j] + bb, bo);
        v = v > 0.0f ? v : 0.0f;
        m = v > m ? v : m;
      }
    }
    atomicMax((int*)&spfd[((size_t)b * 128 + o) * NSTK + s], __float_as_int(m));
  }
}

// ---------------- K2: FPS + out2 gather ----------------
__global__ __launch_bounds__(128) void k_fps(const float* __restrict__ coor, int* __restrict__ fpsidx,
                                             float* __restrict__ out2) {
  int b = blockIdx.x, t = threadIdx.x;
  __shared__ float X[32][132];
  __shared__ float dist[32];
  __shared__ int far_s;
  __shared__ int sel[16];
  for (int idx = t; idx < 32 * 32; idx += 128) {
    int r = idx >> 5, q = idx & 31;
    *(float4*)&X[r][q * 4] = *(const float4*)&coor[((size_t)b * 32 + r) * 128 + q * 4];
  }
  if (t < 32) dist[t] = 1e10f;
  if (t == 0) far_s = 0;
  __syncthreads();
  for (int it = 0; it < 16; it++) {
    int far = far_s;
    if (t == 0) sel[it] = far;
    if (t < 32) {
      float d = 0.0f;
      for (int c = 0; c < 128; c++) { float dd = X[t][c] - X[far][c]; d = fmaf(dd, dd, d); }
      float dm = dist[t];
      dist[t] = d < dm ? d : dm;
    }
    __syncthreads();
    if (t == 0) {
      float best = -1.0f; int bi = 0;
      for (int m = 0; m < 32; m++) if (dist[m] > best) { best = dist[m]; bi = m; }
      far_s = bi;
    }
    __syncthreads();
  }
  if (t < 16) fpsidx[b * 16 + t] = sel[t];
  __syncthreads();
  for (int idx = t; idx < 16 * 32; idx += 128) {
    int j = idx >> 5, q = idx & 31;
    *(float4*)&out2[((size_t)b * 16 + j) * 128 + q * 4] = *(const float4*)&X[sel[j]][q * 4];
  }
}

// ---------------- K3a: sparse graph: build xs, dist 32x32, top2 ----------------
__global__ __launch_bounds__(256) void k_sparse_graph(const float* __restrict__ sf, const float* __restrict__ spfd,
    float* __restrict__ xs, int* __restrict__ idxs) {
  int b = blockIdx.x, t = threadIdx.x;
  __shared__ float X[32][260];
  __shared__ float sq[32];
  __shared__ float D[32][33];
  for (int idx = t; idx < 32 * 256; idx += 256) {
    int n = idx >> 8, c = idx & 255;
    float v = (c < 128) ? sf[((size_t)b * 128 + c) * NSTK + n]
                        : spfd[((size_t)b * 128 + (c - 128)) * NSTK + n];
    X[n][c] = v;
  }
  __syncthreads();
  for (int idx = t; idx < 32 * 64; idx += 256) {
    int n = idx >> 6, q = idx & 63;
    *(float4*)&xs[((size_t)b * 32 + n) * 256 + q * 4] = *(const float4*)&X[n][q * 4];
  }
  if (t < 32) {
    float s = 0.0f;
    for (int c = 0; c < 256; c++) s = fmaf(X[t][c], X[t][c], s);
    sq[t] = s;
  }
  __syncthreads();
  {
    int n = t >> 3;
    for (int mg = 0; mg < 4; mg++) {
      int m = (t & 7) + mg * 8;
      float dot = 0.0f;
      for (int c = 0; c < 256; c++) dot = fmaf(X[n][c], X[m][c], dot);
      D[n][m] = (sq[n] - 2.0f * dot) + sq[m];
    }
  }
  __syncthreads();
  if (t < 32) {
    float d0 = 1e30f, d1 = 1e30f; int i0 = 0, i1 = 0;
    for (int m = 0; m < 32; m++) {
      float d = D[t][m];
      if (d < d0) { d1 = d0; i1 = i0; d0 = d; i0 = m; }
      else if (d < d1) { d1 = d; i1 = m; }
    }
    idxs[(b * 32 + t) * 2 + 0] = i0;
    idxs[(b * 32 + t) * 2 + 1] = i1;
  }
}

// ---------------- K3b: sparse P/Q ----------------
__global__ __launch_bounds__(256) void k_sparse_pq(const float* __restrict__ xs, const float* __restrict__ W,
    float* __restrict__ Ps, float* __restrict__ Qs) {
  int b = blockIdx.x >> 5, n = blockIdx.x & 31;
  int o = threadIdx.x;
  const float* xr = &xs[((size_t)b * 32 + n) * 256];
  float accP = 0.0f, accQ = 0.0f;
  for (int c = 0; c < 256; c++) {
    float xc = xr[c];
    float w1 = W[(size_t)c * 256 + o];
    float w2 = W[(size_t)(c + 256) * 256 + o];
    accP = fmaf(xc, w1 - w2, accP);
    accQ = fmaf(xc, w2, accQ);
  }
  Ps[((size_t)b * 32 + n) * 256 + o] = accP;
  Qs[((size_t)b * 32 + n) * 256 + o] = accQ;
}

// ---------------- K3c: sparse combine (P + Q[nbr] + bias, BN, relu, max over k=2) ----------------
__global__ __launch_bounds__(256) void k_sparse_combine(const float* __restrict__ Ps, const float* __restrict__ Qs,
    const int* __restrict__ idxs, const float* __restrict__ g, const float* __restrict__ cb,
    const float* __restrict__ bt, float* __restrict__ sup) {
  int b = blockIdx.x >> 5, n = blockIdx.x & 31, o = threadIdx.x;
  int i0 = idxs[(b * 32 + n) * 2 + 0], i1 = idxs[(b * 32 + n) * 2 + 1];
  float p = Ps[((size_t)b * 32 + n) * 256 + o];
  float q0 = Qs[((size_t)b * 32 + i0) * 256 + o];
  float q1 = Qs[((size_t)b * 32 + i1) * 256 + o];
  float gg = g[o], bb = cb[o], bo = bt[o];
  float h0 = fmaf(gg, p + q0 + bb, bo); h0 = h0 > 0.0f ? h0 : 0.0f;
  float h1 = fmaf(gg, p + q1 + bb, bo); h1 = h1 > 0.0f ? h1 : 0.0f;
  sup[((size_t)b * 32 + n) * 256 + o] = h0 > h1 ? h0 : h1;
}

// ---------------- K8: gather out0 ----------------
__global__ __launch_bounds__(256) void k_gather_out0(const float* __restrict__ sup, const int* __restrict__ fps,
                                                     float* __restrict__ out0) {
  int b = blockIdx.x, o = threadIdx.x;
  for (int j = 0; j < 16; j++) {
    int n = fps[b * 16 + j];
    out0[((size_t)b * 256 + o) * 16 + j] = sup[((size_t)b * 32 + n) * 256 + o];
  }
}

// ---------------- K4: dense distances + streaming top-10 ----------------
__global__ __launch_bounds__(128, 2) void k_knn(const float* __restrict__ xt, const float* __restrict__ sqd,
    float* __restrict__ pd, int* __restrict__ pi) {
  int bx = blockIdx.x;
  int half = bx & 1, ntile = (bx >> 1) & 127, b = bx >> 8;
  int n0 = ntile * 32;
  int t = threadIdx.x;
  int tn = t & 3, tm = t >> 2;
  const float* X = xt + (size_t)b * NPNT * 256;

  __shared__ float A[32][36];
  __shared__ float Bsm[32][260];
  __shared__ float sqn_l[32], sqm_l[256];
  __shared__ float tau[32];
  __shared__ int cnt[32];
  __shared__ float candd[32][8];
  __shared__ int candm[32][8];
  __shared__ int ovf;

  if (t < 32) { sqn_l[t] = sqd[b * NPNT + n0 + t]; tau[t] = 1e30f; cnt[t] = 0; }
  if (t == 0) ovf = 0;

  float ld[10]; int li[10];
#pragma unroll
  for (int j = 0; j < 10; j++) { ld[j] = 1e30f; li[j] = 0x7fffffff; }

  int qown = n0 >> 8;
  bool own_here = ((qown >> 3) == half);

  for (int tq = 0; tq < 8; tq++) {
    int q;
    if (own_here) {
      if (tq == 0) q = qown;
      else { q = half * 8 + tq - 1; if (q >= qown) q++; }
    } else q = half * 8 + tq;
    int m0 = q * 256;

    float acc[8][8];
#pragma unroll
    for (int i = 0; i < 8; i++)
#pragma unroll
      for (int j = 0; j < 8; j++) acc[i][j] = 0.0f;

    for (int kc = 0; kc < 256; kc += 32) {
      {
        int nl = t >> 2, c4 = t & 3;
        const float* src = X + (size_t)(n0 + nl) * 256 + kc + c4 * 8;
        float4 v0 = *(const float4*)src;
        float4 v1 = *(const float4*)(src + 4);
        int cc = c4 * 8;
        A[cc+0][nl] = v0.x; A[cc+1][nl] = v0.y; A[cc+2][nl] = v0.z; A[cc+3][nl] = v0.w;
        A[cc+4][nl] = v1.x; A[cc+5][nl] = v1.y; A[cc+6][nl] = v1.z; A[cc+7][nl] = v1.w;
      }
      {
        int c4 = t & 7, mb = t >> 3;
#pragma unroll
        for (int rep = 0; rep < 16; rep++) {
          int m = rep * 16 + mb;
          float4 v = *(const float4*)(X + (size_t)(m0 + m) * 256 + kc + c4 * 4);
          int cc = c4 * 4;
          Bsm[cc+0][m] = v.x; Bsm[cc+1][m] = v.y; Bsm[cc+2][m] = v.z; Bsm[cc+3][m] = v.w;
        }
      }
      if (kc == 0) { for (int i2 = t; i2 < 256; i2 += 128) sqm_l[i2] = sqd[b * NPNT + m0 + i2]; }
      __syncthreads();
#pragma unroll 4
      for (int k = 0; k < 32; k++) {
        float av[8], bv[8];
        *(float4*)&av[0] = *(const float4*)&A[k][tn * 8];
        *(float4*)&av[4] = *(const float4*)&A[k][tn * 8 + 4];
        *(float4*)&bv[0] = *(const float4*)&Bsm[k][tm * 8];
        *(float4*)&bv[4] = *(const float4*)&Bsm[k][tm * 8 + 4];
#pragma unroll
        for (int i = 0; i < 8; i++)
#pragma unroll
          for (int j = 0; j < 8; j++)
            acc[i][j] = fmaf(av[i], bv[j], acc[i][j]);
      }
      __syncthreads();
    }

    if (tq == 0) {
      // exact warm-up scan: stash d into Bsm (B tile dead), per-row scan by t<32
#pragma unroll
      for (int i = 0; i < 8; i++) {
        int r = tn * 8 + i; float sn = sqn_l[r];
#pragma unroll
        for (int j = 0; j < 8; j++) {
          int m = tm * 8 + j;
          Bsm[r][m] = (sn - 2.0f * acc[i][j]) + sqm_l[m];
        }
      }
      __syncthreads();
      if (t < 32) {
        for (int m = 0; m < 256; m++) insert10(ld, li, Bsm[t][m], m0 + m);
        tau[t] = ld[9];
      }
      __syncthreads();
    } else {
      unsigned long long pend = 0ull;
#pragma unroll
      for (int i = 0; i < 8; i++) {
        int r = tn * 8 + i; float sn = sqn_l[r];
#pragma unroll
        for (int j = 0; j < 8; j++) {
          float d = (sn - 2.0f * acc[i][j]) + sqm_l[tm * 8 + j];
          acc[i][j] = d;  // keep for retry
          if (d <= tau[r]) {
            int pos = atomicAdd(&cnt[r], 1);
            if (pos < 8) { candd[r][pos] = d; candm[r][pos] = m0 + tm * 8 + j; }
            else { pend |= 1ull << (i * 8 + j); ovf = 1; }
          }
        }
      }
      __syncthreads();
      while (true) {
        if (t < 32) {
          int c = cnt[t]; c = c > 8 ? 8 : c;
          for (int x = 0; x < c; x++) insert10(ld, li, candd[t][x], candm[t][x]);
          tau[t] = ld[9];
        }
        __syncthreads();
        int o = ovf;
        __syncthreads();
        if (!o) break;
        if (t < 32) cnt[t] = 0;
        if (t == 0) ovf = 0;
        __syncthreads();
        if (pend) {
#pragma unroll
          for (int i = 0; i < 8; i++)
#pragma unroll
            for (int j = 0; j < 8; j++) {
              unsigned long long bit = 1ull << (i * 8 + j);
              if (pend & bit) {
                int r = tn * 8 + i;
                float d = acc[i][j];
                if (d <= tau[r]) {
                  int pos = atomicAdd(&cnt[r], 1);
                  if (pos < 8) { candd[r][pos] = d; candm[r][pos] = m0 + tm * 8 + j; pend &= ~bit; }
                  else ovf = 1;
                } else pend &= ~bit;
              }
            }
        }
        __syncthreads();
      }
      // reset for next tile
      if (t < 32) cnt[t] = 0;
      if (t == 0) ovf = 0;
      __syncthreads();
    }
  }

  if (t < 32) {
    size_t row = (size_t)b * NPNT + n0 + t;
#pragma unroll
    for (int j = 0; j < 10; j++) {
      pd[(row * 2 + half) * 10 + j] = ld[j];
      pi[(row * 2 + half) * 10 + j] = li[j];
    }
  }
}

// ---------------- K4b: merge the 2 half-lists ----------------
__global__ __launch_bounds__(256) void k_knn_merge(const float* __restrict__ pd, const int* __restrict__ pi,
                                                   int* __restrict__ knn) {
  int row = blockIdx.x * 256 + threadIdx.x;
  if (row >= 4 * NPNT) return;
  float ld[10]; int li[10];
#pragma unroll
  for (int j = 0; j < 10; j++) { ld[j] = pd[(size_t)row * 20 + j]; li[j] = pi[(size_t)row * 20 + j]; }
#pragma unroll
  for (int j = 0; j < 10; j++) insert10(ld, li, pd[(size_t)row * 20 + 10 + j], pi[(size_t)row * 20 + 10 + j]);
#pragma unroll
  for (int j = 0; j < 10; j++) knn[(size_t)row * 10 + j] = li[j];
}

// ---------------- K5: dense P/Q GEMMs: P = Xt@(W1-W2), Q = Xt@W2 ----------------
__global__ __launch_bounds__(256) void k_pq(const float* __restrict__ xt, const float* __restrict__ W,
    float* __restrict__ P, float* __restrict__ Q) {
  // grid (64, 4, 4): ntile, otile, b
  int n0 = blockIdx.x * 64, o0 = blockIdx.y * 64, b = blockIdx.z;
  int t = threadIdx.x;
  __shared__ float A[32][68];
  __shared__ float B1[32][64], B2[32][64];
  float accP[4][4], accQ[4][4];
#pragma unroll
  for (int i = 0; i < 4; i++)
#pragma unroll
    for (int j = 0; j < 4; j++) { accP[i][j] = 0.0f; accQ[i][j] = 0.0f; }
  int tn = t & 15, to = t >> 4;
  for (int kc = 0; kc < 256; kc += 32) {
    {
      int nl = t >> 2, c4 = t & 3;
      const float* src = &xt[((size_t)b * NPNT + n0 + nl) * 256 + kc + c4 * 8];
      float4 v0 = *(const float4*)src;
      float4 v1 = *(const float4*)(src + 4);
      int cc = c4 * 8;
      A[cc+0][nl] = v0.x; A[cc+1][nl] = v0.y; A[cc+2][nl] = v0.z; A[cc+3][nl] = v0.w;
      A[cc+4][nl] = v1.x; A[cc+5][nl] = v1.y; A[cc+6][nl] = v1.z; A[cc+7][nl] = v1.w;
    }
    {
      int kl = t >> 3, qq = t & 7;
      const float* s1 = &W[(size_t)(kc + kl) * 256 + o0 + qq * 8];
      const float* s2 = &W[(size_t)(kc + kl + 256) * 256 + o0 + qq * 8];
      float4 a0 = *(const float4*)s1, a1 = *(const float4*)(s1 + 4);
      float4 b0 = *(const float4*)s2, b1 = *(const float4*)(s2 + 4);
      *(float4*)&B2[kl][qq * 8] = b0; *(float4*)&B2[kl][qq * 8 + 4] = b1;
      float4 d0, d1;
      d0.x = a0.x - b0.x; d0.y = a0.y - b0.y; d0.z = a0.z - b0.z; d0.w = a0.w - b0.w;
      d1.x = a1.x - b1.x; d1.y = a1.y - b1.y; d1.z = a1.z - b1.z; d1.w = a1.w - b1.w;
      *(float4*)&B1[kl][qq * 8] = d0; *(float4*)&B1[kl][qq * 8 + 4] = d1;
    }
    __syncthreads();
#pragma unroll 4
    for (int k = 0; k < 32; k++) {
      float4 a  = *(const float4*)&A[k][tn * 4];
      float4 w1 = *(const float4*)&B1[k][to * 4];
      float4 w2 = *(const float4*)&B2[k][to * 4];
      float av[4] = {a.x, a.y, a.z, a.w};
      float w1v[4] = {w1.x, w1.y, w1.z, w1.w};
      float w2v[4] = {w2.x, w2.y, w2.z, w2.w};
#pragma unroll
      for (int i = 0; i < 4; i++)
#pragma unroll
        for (int j = 0; j < 4; j++) {
          accP[i][j] = fmaf(av[i], w1v[j], accP[i][j]);
          accQ[i][j] = fmaf(av[i], w2v[j], accQ[i][j]);
        }
    }
    __syncthreads();
  }
#pragma unroll
  for (int i = 0; i < 4; i++) {
    size_t base = ((size_t)b * NPNT + n0 + tn * 4 + i) * 256 + o0 + to * 4;
    float4 vp, vq;
    vp.x = accP[i][0]; vp.y = accP[i][1]; vp.z = accP[i][2]; vp.w = accP[i][3];
    vq.x = accQ[i][0]; vq.y = accQ[i][1]; vq.z = accQ[i][2]; vq.w = accQ[i][3];
    *(float4*)&P[base] = vp;
    *(float4*)&Q[base] = vq;
  }
}

// ---------------- K6: build im2col E for downsample conv (fused dense combine+max) ----------------
__global__ __launch_bounds__(256) void k_build_E(const float* __restrict__ P, const float* __restrict__ Q,
    const int* __restrict__ knn, const int* __restrict__ fps,
    const float* __restrict__ g, const float* __restrict__ cb, const float* __restrict__ bt,
    float* __restrict__ E) {
  // grid (64, 16, 4): pp, j, b
  int pp = blockIdx.x, j = blockIdx.y, b = blockIdx.z;
  int t = threadIdx.x;   // channel i
  int s = fps[b * 16 + j];
  float gg = g[t], bb = cb[t], bo = bt[t];
  float v[3];
#pragma unroll
  for (int dp = 0; dp < 3; dp++) {
    int p = 2 * pp - 1 + dp;
    float val = 0.0f;
    if (p >= 0 && p < 128) {
      int n = s * 128 + p;
      float pv = P[((size_t)b * NPNT + n) * 256 + t] + bb;
      const int* id = &knn[((size_t)b * NPNT + n) * 10];
      float mx = 0.0f;
#pragma unroll
      for (int k = 0; k < 10; k++) {
        float qv = Q[((size_t)b * NPNT + id[k]) * 256 + t];
        float h = fmaf(gg, pv + qv, bo);
        mx = h > mx ? h : mx;
      }
      val = mx;
    }
    v[dp] = val;
  }
  size_t base = ((size_t)(b * 16 + j) * 64 + pp) * 768;
  E[base + 3 * t + 0] = v[0];
  E[base + 3 * t + 1] = v[1];
  E[base + 3 * t + 2] = v[2];
}

// ---------------- K7: downsample GEMM (256 x 1024 x 768) + BN + ReLU ----------------
__global__ __launch_bounds__(256) void k_ds_gemm(const float* __restrict__ Wd, const float* __restrict__ E,
    const float* __restrict__ cb, const float* __restrict__ g, const float* __restrict__ bt,
    float* __restrict__ out1) {
  // grid (16, 4, 4): jtile, otile, b
  int j0 = blockIdx.x * 64, o0 = blockIdx.y * 64, b = blockIdx.z;
  int t = threadIdx.x;
  __shared__ float A[32][68];
  __shared__ float Bs[32][68];
  float acc[4][4];
#pragma unroll
  for (int i = 0; i < 4; i++)
#pragma unroll
    for (int j = 0; j < 4; j++) acc[i][j] = 0.0f;
  int tj = t & 15, to = t >> 4;
  for (int kc = 0; kc < 768; kc += 32) {
    {
      int ol = t >> 2, q = t & 3;
      const float* src = &Wd[(size_t)(o0 + ol) * 768 + kc + q * 8];
      float4 v0 = *(const float4*)src, v1 = *(const float4*)(src + 4);
      int cc = q * 8;
      A[cc+0][ol] = v0.x; A[cc+1][ol] = v0.y; A[cc+2][ol] = v0.z; A[cc+3][ol] = v0.w;
      A[cc+4][ol] = v1.x; A[cc+5][ol] = v1.y; A[cc+6][ol] = v1.z; A[cc+7][ol] = v1.w;
    }
    {
      int jl = t >> 2, q = t & 3;
      const float* src = &E[((size_t)b * 1024 + j0 + jl) * 768 + kc + q * 8];
      float4 v0 = *(const float4*)src, v1 = *(const float4*)(src + 4);
      int cc = q * 8;
      Bs[cc+0][jl] = v0.x; Bs[cc+1][jl] = v0.y; Bs[cc+2][jl] = v0.z; Bs[cc+3][jl] = v0.w;
      Bs[cc+4][jl] = v1.x; Bs[cc+5][jl] = v1.y; Bs[cc+6][jl] = v1.z; Bs[cc+7][jl] = v1.w;
    }
    __syncthreads();
#pragma unroll 4
    for (int k = 0; k < 32; k++) {
      float4 a = *(const float4*)&A[k][to * 4];
      float4 bv = *(const float4*)&Bs[k][tj * 4];
      float av[4] = {a.x, a.y, a.z, a.w};
      float bb[4] = {bv.x, bv.y, bv.z, bv.w};
#pragma unroll
      for (int i = 0; i < 4; i++)
#pragma unroll
        for (int j = 0; j < 4; j++)
          acc[i][j] = fmaf(av[i], bb[j], acc[i][j]);
    }
    __syncthreads();
  }
#pragma unroll
  for (int i = 0; i < 4; i++) {
    int o = o0 + to * 4 + i;
    float gg = g[o], bb = cb[o], bo = bt[o];
    float4 v;
    float x0 = fmaf(gg, acc[i][0] + bb, bo); v.x = x0 > 0.0f ? x0 : 0.0f;
    float x1 = fmaf(gg, acc[i][1] + bb, bo); v.y = x1 > 0.0f ? x1 : 0.0f;
    float x2 = fmaf(gg, acc[i][2] + bb, bo); v.z = x2 > 0.0f ? x2 : 0.0f;
    float x3 = fmaf(gg, acc[i][3] + bb, bo); v.w = x3 > 0.0f ? x3 : 0.0f;
    *(float4*)&out1[((size_t)b * 256 + o) * 1024 + j0 + tj * 4] = v;
  }
}

extern "C" void kernel_launch(void* const* d_in, const int* in_sizes, int n_in,
                              void* d_out, int out_size, void* d_ws, size_t ws_size,
                              hipStream_t stream) {
  (void)in_sizes; (void)n_in; (void)out_size; (void)ws_size;
  const float* sf    = (const float*)d_in[0];
  const float* df    = (const float*)d_in[1];
  const float* coor  = (const float*)d_in[2];
  const float* d2sw  = (const float*)d_in[3];
  const float* d2sb  = (const float*)d_in[4];
  const float* d2sg  = (const float*)d_in[5];
  const float* d2sbt = (const float*)d_in[6];
  const float* spW   = (const float*)d_in[7];
  const float* spb   = (const float*)d_in[8];
  const float* spg   = (const float*)d_in[9];
  const float* spbt  = (const float*)d_in[10];
  const float* dnW   = (const float*)d_in[11];
  const float* dnb   = (const float*)d_in[12];
  const float* dng   = (const float*)d_in[13];
  const float* dnbt  = (const float*)d_in[14];
  const float* dsw   = (const float*)d_in[15];
  const float* dsb   = (const float*)d_in[16];
  const float* dsg   = (const float*)d_in[17];
  const float* dsbt  = (const float*)d_in[18];

  float* ws   = (float*)d_ws;
  float* XT   = ws + OFF_XT;
  float* P    = ws + OFF_P;
  float* Q    = ws + OFF_Q;
  float* SQD  = ws + OFF_SQD;
  float* SPFD = ws + OFF_SPFD;
  float* XS   = ws + OFF_XS;
  float* PS   = ws + OFF_PS;
  float* QS   = ws + OFF_QS;
  float* SUP  = ws + OFF_SUP;
  float* PDL  = ws + OFF_PDL;
  int*   PIL  = (int*)(ws + OFF_PIL);
  int*   KNN  = (int*)(ws + OFF_KNN);
  int*   IDXS = (int*)(ws + OFF_IDXS);
  int*   FPS  = (int*)(ws + OFF_FPS);
  float* E    = XT;  // alias: XT dead after k_pq

  float* out0 = (float*)d_out;
  float* out1 = out0 + 16384;
  float* out2 = out1 + 1048576;

  hipMemsetAsync(SPFD, 0, 16384 * sizeof(float), stream);

  k_build_xt_dense<<<dim3(4, 64, 4), 256, 0, stream>>>(df, XT);
  k_build_xt_sparse<<<dim3(2048), 256, 0, stream>>>(sf, XT);
  k_sqd<<<dim3(4096), 256, 0, stream>>>(XT, SQD);
  k_d2s<<<dim3(4, 2, 64), 256, 0, stream>>>(df, d2sw, d2sb, d2sg, d2sbt, SPFD);
  k_fps<<<dim3(4), 128, 0, stream>>>(coor, FPS, out2);
  k_sparse_graph<<<dim3(4), 256, 0, stream>>>(sf, SPFD, XS, IDXS);
  k_sparse_pq<<<dim3(128), 256, 0, stream>>>(XS, spW, PS, QS);
  k_sparse_combine<<<dim3(128), 256, 0, stream>>>(PS, QS, IDXS, spg, spb, spbt, SUP);
  k_gather_out0<<<dim3(4), 256, 0, stream>>>(SUP, FPS, out0);
  k_knn<<<dim3(1024), 128, 0, stream>>>(XT, SQD, PDL, PIL);
  k_knn_merge<<<dim3(64), 256, 0, stream>>>(PDL, PIL, KNN);
  k_pq<<<dim3(64, 4, 4), 256, 0, stream>>>(XT, dnW, P, Q);
  k_build_E<<<dim3(64, 16, 4), 256, 0, stream>>>(P, Q, KNN, FPS, dng, dnb, dnbt, E);
  k_ds_gemm<<<dim3(16, 4, 4), 256, 0, stream>>>(dsw, E, dsb, dsg, dsbt, out1);
}

// Round 2
// 1392.616 us; speedup vs baseline: 1.0321x; 1.0321x over previous
//
#include <hip/hip_runtime.h>

#define NPNT 4096
#define NSTK 32

// ---------------- workspace layout (floats) ----------------
static const size_t OFF_XT   = 0;          // 4*4096*256 = 4194304 (aliased by E later: 4*1024*768)
static const size_t OFF_P    = 4194304;    // 4194304
static const size_t OFF_Q    = 8388608;    // 4194304
static const size_t OFF_SQD  = 12582912;   // 16384
static const size_t OFF_SPFD = 12599296;   // 16384
static const size_t OFF_XS   = 12615680;   // 32768
static const size_t OFF_PS   = 12648448;   // 32768
static const size_t OFF_QS   = 12681216;   // 32768
static const size_t OFF_SUP  = 12713984;   // 32768
static const size_t OFF_PDL  = 12746752;   // 327680
static const size_t OFF_PIL  = 13074432;   // 327680 (int)
static const size_t OFF_KNN  = 13402112;   // 163840 (int)
static const size_t OFF_IDXS = 13565952;   // 256 (int)
static const size_t OFF_FPS  = 13566208;   // 64 (int)
static const size_t OFF_SD   = 13566272;   // 4096 (stroke-pair dists, 4*32*32)

__device__ __forceinline__ bool lexlt(float d1, int i1, float d2, int i2) {
  return (d1 < d2) || (d1 == d2 && i1 < i2);
}
__device__ __forceinline__ void insert10(float ld[10], int li[10], float d, int i) {
  if (!lexlt(d, i, ld[9], li[9])) return;
  ld[9] = d; li[9] = i;
#pragma unroll
  for (int j = 9; j > 0; j--) {
    if (lexlt(ld[j], li[j], ld[j-1], li[j-1])) {
      float td = ld[j]; ld[j] = ld[j-1]; ld[j-1] = td;
      int ti = li[j]; li[j] = li[j-1]; li[j-1] = ti;
    }
  }
}

// ---------------- K0a: Xt dense half (transpose dense_fea [b,c,n] -> Xt[b,n,c]) ----------------
__global__ __launch_bounds__(256) void k_build_xt_dense(const float* __restrict__ df, float* __restrict__ xt) {
  // grid (4, 64, 4): b, ntile(64), ctile(32)
  int b = blockIdx.x, n0 = blockIdx.y * 64, c0 = blockIdx.z * 32;
  __shared__ float T[32][68];
  int t = threadIdx.x;
  {
    int cl = t >> 3, seg = t & 7;
#pragma unroll
    for (int r = 0; r < 2; r++) {
      int f4 = seg * 2 + r;
      float4 v = *(const float4*)&df[((size_t)b * 128 + c0 + cl) * NPNT + n0 + f4 * 4];
      *(float4*)&T[cl][f4 * 4] = v;
    }
  }
  __syncthreads();
  {
    int nl = t >> 2, q = t & 3;
    float4 v0, v1;
    v0.x = T[q*8+0][nl]; v0.y = T[q*8+1][nl]; v0.z = T[q*8+2][nl]; v0.w = T[q*8+3][nl];
    v1.x = T[q*8+4][nl]; v1.y = T[q*8+5][nl]; v1.z = T[q*8+6][nl]; v1.w = T[q*8+7][nl];
    float* dst = &xt[((size_t)b * NPNT + n0 + nl) * 256 + c0 + q * 8];
    *(float4*)dst = v0; *(float4*)(dst + 4) = v1;
  }
}

// ---------------- K0b: Xt sparse half (broadcast sparse_fea onto points) ----------------
__global__ __launch_bounds__(256) void k_build_xt_sparse(const float* __restrict__ sf, float* __restrict__ xt) {
  int tid = blockIdx.x * 256 + threadIdx.x;   // 2048 blocks: 4*4096*32 f4 units
  int b = tid >> 17;
  int rem = tid & 131071;
  int n = rem >> 5, q = rem & 31;
  int s = n >> 7;
  float4 v;
  v.x = sf[((size_t)b * 128 + q*4+0) * NSTK + s];
  v.y = sf[((size_t)b * 128 + q*4+1) * NSTK + s];
  v.z = sf[((size_t)b * 128 + q*4+2) * NSTK + s];
  v.w = sf[((size_t)b * 128 + q*4+3) * NSTK + s];
  *(float4*)&xt[((size_t)b * NPNT + n) * 256 + 128 + q * 4] = v;
}

// ---------------- K0c: sqd[b*4096+n] = sum over DENSE 128 ch of df^2 ----------------
__global__ __launch_bounds__(256) void k_sqd128(const float* __restrict__ df, float* __restrict__ sqd) {
  // grid (4, 16): b, ntile(256)
  int b = blockIdx.x, n0 = blockIdx.y * 256;
  int n = n0 + threadIdx.x;
  float acc = 0.0f;
#pragma unroll 4
  for (int c = 0; c < 128; c++) {
    float v = df[((size_t)b * 128 + c) * NPNT + n];
    acc = fmaf(v, v, acc);
  }
  sqd[(size_t)b * NPNT + n] = acc;
}

// ---------------- K0d: SD[b][s][u] = ||sf[:,s] - sf[:,u]||^2 (stroke-level sparse dist) ------
__global__ __launch_bounds__(256) void k_sd(const float* __restrict__ sf, float* __restrict__ SD) {
  int b = blockIdx.x, t = threadIdx.x;
  __shared__ float X[32][132];
  for (int idx = t; idx < 128 * 32; idx += 256) {
    int c = idx >> 5, s = idx & 31;
    X[s][c] = sf[((size_t)b * 128 + c) * NSTK + s];
  }
  __syncthreads();
#pragma unroll
  for (int rep = 0; rep < 4; rep++) {
    int p = t + rep * 256;
    int s = p >> 5, u = p & 31;
    float acc = 0.0f;
    for (int c = 0; c < 128; c++) {
      float d = X[s][c] - X[u][c];
      acc = fmaf(d, d, acc);
    }
    SD[(size_t)b * 1024 + p] = acc;
  }
}

// ---------------- K1: DenseToSparse conv(1,3)+BN+ReLU+max over points ----------------
__global__ __launch_bounds__(256) void k_d2s(const float* __restrict__ df, const float* __restrict__ w,
    const float* __restrict__ cb, const float* __restrict__ g, const float* __restrict__ bt,
    float* __restrict__ spfd) {
  // grid (4, 2, 64): b, otile(64), ntile(64)
  int b = blockIdx.x, o0 = blockIdx.y * 64, n0 = blockIdx.z * 64;
  int t = threadIdx.x;
  __shared__ float A[96][64];   // [iloc*3+kw][o]
  __shared__ float Bs[32][68];  // [iloc][n halo]
  float acc[4][4];
#pragma unroll
  for (int i = 0; i < 4; i++)
#pragma unroll
    for (int j = 0; j < 4; j++) acc[i][j] = 0.0f;
  int tn = t & 15, to = t >> 4;
  for (int ic = 0; ic < 128; ic += 32) {
    {
      int ol = t >> 2, q = t & 3;
      const float* src = &w[((size_t)(o0 + ol) * 128 + ic) * 3 + q * 24];
#pragma unroll
      for (int r = 0; r < 6; r++) {
        float4 v = *(const float4*)&src[r * 4];
        int e = q * 24 + r * 4;
        A[e+0][ol] = v.x; A[e+1][ol] = v.y; A[e+2][ol] = v.z; A[e+3][ol] = v.w;
      }
    }
    for (int idx = t; idx < 32 * 17; idx += 256) {
      int row = idx / 17, f4 = idx % 17;
      int nb = n0 + f4 * 4;
      const float* srow = &df[((size_t)b * 128 + ic + row) * NPNT];
      float4 v;
      if (nb + 3 < NPNT) v = *(const float4*)&srow[nb];
      else {
        v.x = srow[nb   < NPNT ? nb   : NPNT-1];
        v.y = srow[nb+1 < NPNT ? nb+1 : NPNT-1];
        v.z = srow[nb+2 < NPNT ? nb+2 : NPNT-1];
        v.w = srow[nb+3 < NPNT ? nb+3 : NPNT-1];
      }
      *(float4*)&Bs[row][f4 * 4] = v;
    }
    __syncthreads();
#pragma unroll 2
    for (int ii = 0; ii < 32; ii++) {
      float bv[8];
      *(float4*)&bv[0] = *(const float4*)&Bs[ii][tn * 4];
      *(float4*)&bv[4] = *(const float4*)&Bs[ii][tn * 4 + 4];
#pragma unroll
      for (int kw = 0; kw < 3; kw++) {
        float4 av = *(const float4*)&A[ii * 3 + kw][to * 4];
#pragma unroll
        for (int j = 0; j < 4; j++) {
          float bvj = bv[kw + j];
          acc[0][j] = fmaf(av.x, bvj, acc[0][j]);
          acc[1][j] = fmaf(av.y, bvj, acc[1][j]);
          acc[2][j] = fmaf(av.z, bvj, acc[2][j]);
          acc[3][j] = fmaf(av.w, bvj, acc[3][j]);
        }
      }
    }
    __syncthreads();
  }
  int s = n0 >> 7;
#pragma unroll
  for (int i = 0; i < 4; i++) {
    int o = o0 + to * 4 + i;
    float gg = g[o], bb = cb[o], bo = bt[o];
    float m = 0.0f;
#pragma unroll
    for (int j = 0; j < 4; j++) {
      int n = n0 + tn * 4 + j;
      int p = n & 127;
      if (p < 126) {
        float v = fmaf(gg, acc[i][j] + bb, bo);
        v = v > 0.0f ? v : 0.0f;
        m = v > m ? v : m;
      }
    }
    atomicMax((int*)&spfd[((size_t)b * 128 + o) * NSTK + s], __float_as_int(m));
  }
}

// ---------------- K2: FPS + out2 gather ----------------
__global__ __launch_bounds__(128) void k_fps(const float* __restrict__ coor, int* __restrict__ fpsidx,
                                             float* __restrict__ out2) {
  int b = blockIdx.x, t = threadIdx.x;
  __shared__ float X[32][132];
  __shared__ float dist[32];
  __shared__ int far_s;
  __shared__ int sel[16];
  for (int idx = t; idx < 32 * 32; idx += 128) {
    int r = idx >> 5, q = idx & 31;
    *(float4*)&X[r][q * 4] = *(const float4*)&coor[((size_t)b * 32 + r) * 128 + q * 4];
  }
  if (t < 32) dist[t] = 1e10f;
  if (t == 0) far_s = 0;
  __syncthreads();
  for (int it = 0; it < 16; it++) {
    int far = far_s;
    if (t == 0) sel[it] = far;
    if (t < 32) {
      float d = 0.0f;
      for (int c = 0; c < 128; c++) { float dd = X[t][c] - X[far][c]; d = fmaf(dd, dd, d); }
      float dm = dist[t];
      dist[t] = d < dm ? d : dm;
    }
    __syncthreads();
    if (t == 0) {
      float best = -1.0f; int bi = 0;
      for (int m = 0; m < 32; m++) if (dist[m] > best) { best = dist[m]; bi = m; }
      far_s = bi;
    }
    __syncthreads();
  }
  if (t < 16) fpsidx[b * 16 + t] = sel[t];
  __syncthreads();
  for (int idx = t; idx < 16 * 32; idx += 128) {
    int j = idx >> 5, q = idx & 31;
    *(float4*)&out2[((size_t)b * 16 + j) * 128 + q * 4] = *(const float4*)&X[sel[j]][q * 4];
  }
}

// ---------------- K3a: sparse graph: build xs, dist 32x32, top2 ----------------
__global__ __launch_bounds__(256) void k_sparse_graph(const float* __restrict__ sf, const float* __restrict__ spfd,
    float* __restrict__ xs, int* __restrict__ idxs) {
  int b = blockIdx.x, t = threadIdx.x;
  __shared__ float X[32][260];
  __shared__ float sq[32];
  __shared__ float D[32][33];
  for (int idx = t; idx < 32 * 256; idx += 256) {
    int n = idx >> 8, c = idx & 255;
    float v = (c < 128) ? sf[((size_t)b * 128 + c) * NSTK + n]
                        : spfd[((size_t)b * 128 + (c - 128)) * NSTK + n];
    X[n][c] = v;
  }
  __syncthreads();
  for (int idx = t; idx < 32 * 64; idx += 256) {
    int n = idx >> 6, q = idx & 63;
    *(float4*)&xs[((size_t)b * 32 + n) * 256 + q * 4] = *(const float4*)&X[n][q * 4];
  }
  if (t < 32) {
    float s = 0.0f;
    for (int c = 0; c < 256; c++) s = fmaf(X[t][c], X[t][c], s);
    sq[t] = s;
  }
  __syncthreads();
  {
    int n = t >> 3;
    for (int mg = 0; mg < 4; mg++) {
      int m = (t & 7) + mg * 8;
      float dot = 0.0f;
      for (int c = 0; c < 256; c++) dot = fmaf(X[n][c], X[m][c], dot);
      D[n][m] = (sq[n] - 2.0f * dot) + sq[m];
    }
  }
  __syncthreads();
  if (t < 32) {
    float d0 = 1e30f, d1 = 1e30f; int i0 = 0, i1 = 0;
    for (int m = 0; m < 32; m++) {
      float d = D[t][m];
      if (d < d0) { d1 = d0; i1 = i0; d0 = d; i0 = m; }
      else if (d < d1) { d1 = d; i1 = m; }
    }
    idxs[(b * 32 + t) * 2 + 0] = i0;
    idxs[(b * 32 + t) * 2 + 1] = i1;
  }
}

// ---------------- K3b: sparse P/Q ----------------
__global__ __launch_bounds__(256) void k_sparse_pq(const float* __restrict__ xs, const float* __restrict__ W,
    float* __restrict__ Ps, float* __restrict__ Qs) {
  int b = blockIdx.x >> 5, n = blockIdx.x & 31;
  int o = threadIdx.x;
  const float* xr = &xs[((size_t)b * 32 + n) * 256];
  float accP = 0.0f, accQ = 0.0f;
  for (int c = 0; c < 256; c++) {
    float xc = xr[c];
    float w1 = W[(size_t)c * 256 + o];
    float w2 = W[(size_t)(c + 256) * 256 + o];
    accP = fmaf(xc, w1 - w2, accP);
    accQ = fmaf(xc, w2, accQ);
  }
  Ps[((size_t)b * 32 + n) * 256 + o] = accP;
  Qs[((size_t)b * 32 + n) * 256 + o] = accQ;
}

// ---------------- K3c: sparse combine ----------------
__global__ __launch_bounds__(256) void k_sparse_combine(const float* __restrict__ Ps, const float* __restrict__ Qs,
    const int* __restrict__ idxs, const float* __restrict__ g, const float* __restrict__ cb,
    const float* __restrict__ bt, float* __restrict__ sup) {
  int b = blockIdx.x >> 5, n = blockIdx.x & 31, o = threadIdx.x;
  int i0 = idxs[(b * 32 + n) * 2 + 0], i1 = idxs[(b * 32 + n) * 2 + 1];
  float p = Ps[((size_t)b * 32 + n) * 256 + o];
  float q0 = Qs[((size_t)b * 32 + i0) * 256 + o];
  float q1 = Qs[((size_t)b * 32 + i1) * 256 + o];
  float gg = g[o], bb = cb[o], bo = bt[o];
  float h0 = fmaf(gg, p + q0 + bb, bo); h0 = h0 > 0.0f ? h0 : 0.0f;
  float h1 = fmaf(gg, p + q1 + bb, bo); h1 = h1 > 0.0f ? h1 : 0.0f;
  sup[((size_t)b * 32 + n) * 256 + o] = h0 > h1 ? h0 : h1;
}

// ---------------- K8: gather out0 ----------------
__global__ __launch_bounds__(256) void k_gather_out0(const float* __restrict__ sup, const int* __restrict__ fps,
                                                     float* __restrict__ out0) {
  int b = blockIdx.x, o = threadIdx.x;
  for (int j = 0; j < 16; j++) {
    int n = fps[b * 16 + j];
    out0[((size_t)b * 256 + o) * 16 + j] = sup[((size_t)b * 32 + n) * 256 + o];
  }
}

// ---------------- K4: dense kNN: dist = dense128 GEMM + stroke SD; streaming top-10 ---------
// grid (2, 64, 4): m-half, rowblock(64 rows), b. 256 threads, 2 blocks/CU.
__global__ __launch_bounds__(256, 2) void k_knn(const float* __restrict__ df, const float* __restrict__ sqd,
    const float* __restrict__ SD, float* __restrict__ pd, int* __restrict__ pi) {
  const int h = blockIdx.x, rb = blockIdx.y, b = blockIdx.z;
  const int n0 = rb * 64;
  const int s_stk = n0 >> 7;
  const int t = threadIdx.x;
  const int tn = t & 15, tm = t >> 4;

  __shared__ float A[32][68];     // [k][n]
  __shared__ float Bm[32][132];   // [k][m]
  __shared__ float D[64][132];    // distance tile
  __shared__ float snl[64];
  __shared__ float sml[128];

  if (t < 64) snl[t] = sqd[(size_t)b * NPNT + n0 + t];

  float ld[10]; int li[10];
#pragma unroll
  for (int j = 0; j < 10; j++) { ld[j] = 1e30f; li[j] = 0x7fffffff; }

  const float* dfb = df + (size_t)b * 128 * NPNT;

  for (int mt = 0; mt < 16; mt++) {
    const int mb = h * 2048 + mt * 128;
    const int u0 = mb >> 7;
    const float SDv = SD[((size_t)b * 32 + s_stk) * 32 + u0];
    if (t < 128) sml[t] = sqd[(size_t)b * NPNT + mb + t];

    float acc[4][8];
#pragma unroll
    for (int i = 0; i < 4; i++)
#pragma unroll
      for (int j = 0; j < 8; j++) acc[i][j] = 0.0f;

    for (int kc = 0; kc < 128; kc += 32) {
      // stage A: 32 k x 64 n, coalesced from c-major df
      {
        int nf4 = t & 15, cl = t >> 4;
#pragma unroll
        for (int r2 = 0; r2 < 2; r2++) {
          int k = cl + r2 * 16;
          float4 v = *(const float4*)&dfb[(size_t)(kc + k) * NPNT + n0 + nf4 * 4];
          *(float4*)&A[k][nf4 * 4] = v;
        }
      }
      // stage B: 32 k x 128 m
      {
        int mf4 = t & 31, cl = t >> 5;
#pragma unroll
        for (int r2 = 0; r2 < 4; r2++) {
          int k = cl + r2 * 8;
          float4 v = *(const float4*)&dfb[(size_t)(kc + k) * NPNT + mb + mf4 * 4];
          *(float4*)&Bm[k][mf4 * 4] = v;
        }
      }
      __syncthreads();
#pragma unroll 8
      for (int k = 0; k < 32; k++) {
        float4 a = *(const float4*)&A[k][tn * 4];
        float4 b0 = *(const float4*)&Bm[k][tm * 8];
        float4 b1 = *(const float4*)&Bm[k][tm * 8 + 4];
        float av[4] = {a.x, a.y, a.z, a.w};
        float bv[8] = {b0.x, b0.y, b0.z, b0.w, b1.x, b1.y, b1.z, b1.w};
#pragma unroll
        for (int i = 0; i < 4; i++)
#pragma unroll
          for (int j = 0; j < 8; j++)
            acc[i][j] = fmaf(av[i], bv[j], acc[i][j]);
      }
      __syncthreads();
    }

    // assemble D tile: d = (sn + SD) - 2*dot + sm
#pragma unroll
    for (int i = 0; i < 4; i++) {
      int r = tn * 4 + i;
      float sn = snl[r] + SDv;
      float4 w0, w1;
      w0.x = sn - 2.0f * acc[i][0] + sml[tm*8+0];
      w0.y = sn - 2.0f * acc[i][1] + sml[tm*8+1];
      w0.z = sn - 2.0f * acc[i][2] + sml[tm*8+2];
      w0.w = sn - 2.0f * acc[i][3] + sml[tm*8+3];
      w1.x = sn - 2.0f * acc[i][4] + sml[tm*8+4];
      w1.y = sn - 2.0f * acc[i][5] + sml[tm*8+5];
      w1.z = sn - 2.0f * acc[i][6] + sml[tm*8+6];
      w1.w = sn - 2.0f * acc[i][7] + sml[tm*8+7];
      *(float4*)&D[r][tm * 8] = w0;
      *(float4*)&D[r][tm * 8 + 4] = w1;
    }
    __syncthreads();

    // selection: 4 threads per row, 32 cols each, private top-10
    {
      int r = t >> 2, sl = t & 3;
#pragma unroll
      for (int jj = 0; jj < 8; jj++) {
        float4 dv = *(const float4*)&D[r][sl * 32 + jj * 4];
        int ib = mb + sl * 32 + jj * 4;
        insert10(ld, li, dv.x, ib + 0);
        insert10(ld, li, dv.y, ib + 1);
        insert10(ld, li, dv.z, ib + 2);
        insert10(ld, li, dv.w, ib + 3);
      }
    }
    // no barrier needed here: next iteration's staging doesn't touch D,
    // and the post-staging barrier orders everything before the next GEMM.
  }

  // merge the 4 per-slice lists of each row
  __syncthreads();
  {
    int r = t >> 2, sl = t & 3;
    int* BI = (int*)&Bm[0][0];
#pragma unroll
    for (int j = 0; j < 10; j++) {
      D[r][sl * 10 + j] = ld[j];
      BI[r * 40 + sl * 10 + j] = li[j];
    }
  }
  __syncthreads();
  if (t < 64) {
    const int* BI = (const int*)&Bm[0][0];
    float fd[10]; int fi[10];
#pragma unroll
    for (int j = 0; j < 10; j++) { fd[j] = 1e30f; fi[j] = 0x7fffffff; }
    for (int x = 0; x < 40; x++) insert10(fd, fi, D[t][x], BI[t * 40 + x]);
    size_t row = (size_t)b * NPNT + n0 + t;
#pragma unroll
    for (int j = 0; j < 10; j++) {
      pd[(row * 2 + h) * 10 + j] = fd[j];
      pi[(row * 2 + h) * 10 + j] = fi[j];
    }
  }
}

// ---------------- K4b: merge the 2 half-lists ----------------
__global__ __launch_bounds__(256) void k_knn_merge(const float* __restrict__ pd, const int* __restrict__ pi,
                                                   int* __restrict__ knn) {
  int row = blockIdx.x * 256 + threadIdx.x;
  if (row >= 4 * NPNT) return;
  float ld[10]; int li[10];
#pragma unroll
  for (int j = 0; j < 10; j++) { ld[j] = pd[(size_t)row * 20 + j]; li[j] = pi[(size_t)row * 20 + j]; }
#pragma unroll
  for (int j = 0; j < 10; j++) insert10(ld, li, pd[(size_t)row * 20 + 10 + j], pi[(size_t)row * 20 + 10 + j]);
#pragma unroll
  for (int j = 0; j < 10; j++) knn[(size_t)row * 10 + j] = li[j];
}

// ---------------- K5: dense P/Q GEMMs: P = Xt@(W1-W2), Q = Xt@W2 ----------------
__global__ __launch_bounds__(256) void k_pq(const float* __restrict__ xt, const float* __restrict__ W,
    float* __restrict__ P, float* __restrict__ Q) {
  // grid (64, 4, 4): ntile, otile, b
  int n0 = blockIdx.x * 64, o0 = blockIdx.y * 64, b = blockIdx.z;
  int t = threadIdx.x;
  __shared__ float A[32][68];
  __shared__ float B1[32][64], B2[32][64];
  float accP[4][4], accQ[4][4];
#pragma unroll
  for (int i = 0; i < 4; i++)
#pragma unroll
    for (int j = 0; j < 4; j++) { accP[i][j] = 0.0f; accQ[i][j] = 0.0f; }
  int tn = t & 15, to = t >> 4;
  for (int kc = 0; kc < 256; kc += 32) {
    {
      int nl = t >> 2, c4 = t & 3;
      const float* src = &xt[((size_t)b * NPNT + n0 + nl) * 256 + kc + c4 * 8];
      float4 v0 = *(const float4*)src;
      float4 v1 = *(const float4*)(src + 4);
      int cc = c4 * 8;
      A[cc+0][nl] = v0.x; A[cc+1][nl] = v0.y; A[cc+2][nl] = v0.z; A[cc+3][nl] = v0.w;
      A[cc+4][nl] = v1.x; A[cc+5][nl] = v1.y; A[cc+6][nl] = v1.z; A[cc+7][nl] = v1.w;
    }
    {
      int kl = t >> 3, qq = t & 7;
      const float* s1 = &W[(size_t)(kc + kl) * 256 + o0 + qq * 8];
      const float* s2 = &W[(size_t)(kc + kl + 256) * 256 + o0 + qq * 8];
      float4 a0 = *(const float4*)s1, a1 = *(const float4*)(s1 + 4);
      float4 b0 = *(const float4*)s2, b1 = *(const float4*)(s2 + 4);
      *(float4*)&B2[kl][qq * 8] = b0; *(float4*)&B2[kl][qq * 8 + 4] = b1;
      float4 d0, d1;
      d0.x = a0.x - b0.x; d0.y = a0.y - b0.y; d0.z = a0.z - b0.z; d0.w = a0.w - b0.w;
      d1.x = a1.x - b1.x; d1.y = a1.y - b1.y; d1.z = a1.z - b1.z; d1.w = a1.w - b1.w;
      *(float4*)&B1[kl][qq * 8] = d0; *(float4*)&B1[kl][qq * 8 + 4] = d1;
    }
    __syncthreads();
#pragma unroll 4
    for (int k = 0; k < 32; k++) {
      float4 a  = *(const float4*)&A[k][tn * 4];
      float4 w1 = *(const float4*)&B1[k][to * 4];
      float4 w2 = *(const float4*)&B2[k][to * 4];
      float av[4] = {a.x, a.y, a.z, a.w};
      float w1v[4] = {w1.x, w1.y, w1.z, w1.w};
      float w2v[4] = {w2.x, w2.y, w2.z, w2.w};
#pragma unroll
      for (int i = 0; i < 4; i++)
#pragma unroll
        for (int j = 0; j < 4; j++) {
          accP[i][j] = fmaf(av[i], w1v[j], accP[i][j]);
          accQ[i][j] = fmaf(av[i], w2v[j], accQ[i][j]);
        }
    }
    __syncthreads();
  }
#pragma unroll
  for (int i = 0; i < 4; i++) {
    size_t base = ((size_t)b * NPNT + n0 + tn * 4 + i) * 256 + o0 + to * 4;
    float4 vp, vq;
    vp.x = accP[i][0]; vp.y = accP[i][1]; vp.z = accP[i][2]; vp.w = accP[i][3];
    vq.x = accQ[i][0]; vq.y = accQ[i][1]; vq.z = accQ[i][2]; vq.w = accQ[i][3];
    *(float4*)&P[base] = vp;
    *(float4*)&Q[base] = vq;
  }
}

// ---------------- K6: build im2col E for downsample conv (fused dense combine+max) ----------------
__global__ __launch_bounds__(256) void k_build_E(const float* __restrict__ P, const float* __restrict__ Q,
    const int* __restrict__ knn, const int* __restrict__ fps,
    const float* __restrict__ g, const float* __restrict__ cb, const float* __restrict__ bt,
    float* __restrict__ E) {
  // grid (64, 16, 4): pp, j, b
  int pp = blockIdx.x, j = blockIdx.y, b = blockIdx.z;
  int t = threadIdx.x;   // channel i
  int s = fps[b * 16 + j];
  float gg = g[t], bb = cb[t], bo = bt[t];
  float v[3];
#pragma unroll
  for (int dp = 0; dp < 3; dp++) {
    int p = 2 * pp - 1 + dp;
    float val = 0.0f;
    if (p >= 0 && p < 128) {
      int n = s * 128 + p;
      float pv = P[((size_t)b * NPNT + n) * 256 + t] + bb;
      const int* id = &knn[((size_t)b * NPNT + n) * 10];
      float mx = 0.0f;
#pragma unroll
      for (int k = 0; k < 10; k++) {
        float qv = Q[((size_t)b * NPNT + id[k]) * 256 + t];
        float h = fmaf(gg, pv + qv, bo);
        mx = h > mx ? h : mx;
      }
      val = mx;
    }
    v[dp] = val;
  }
  size_t base = ((size_t)(b * 16 + j) * 64 + pp) * 768;
  E[base + 3 * t + 0] = v[0];
  E[base + 3 * t + 1] = v[1];
  E[base + 3 * t + 2] = v[2];
}

// ---------------- K7: downsample GEMM (256 x 1024 x 768) + BN + ReLU ----------------
__global__ __launch_bounds__(256) void k_ds_gemm(const float* __restrict__ Wd, const float* __restrict__ E,
    const float* __restrict__ cb, const float* __restrict__ g, const float* __restrict__ bt,
    float* __restrict__ out1) {
  // grid (16, 4, 4): jtile, otile, b
  int j0 = blockIdx.x * 64, o0 = blockIdx.y * 64, b = blockIdx.z;
  int t = threadIdx.x;
  __shared__ float A[32][68];
  __shared__ float Bs[32][68];
  float acc[4][4];
#pragma unroll
  for (int i = 0; i < 4; i++)
#pragma unroll
    for (int j = 0; j < 4; j++) acc[i][j] = 0.0f;
  int tj = t & 15, to = t >> 4;
  for (int kc = 0; kc < 768; kc += 32) {
    {
      int ol = t >> 2, q = t & 3;
      const float* src = &Wd[(size_t)(o0 + ol) * 768 + kc + q * 8];
      float4 v0 = *(const float4*)src, v1 = *(const float4*)(src + 4);
      int cc = q * 8;
      A[cc+0][ol] = v0.x; A[cc+1][ol] = v0.y; A[cc+2][ol] = v0.z; A[cc+3][ol] = v0.w;
      A[cc+4][ol] = v1.x; A[cc+5][ol] = v1.y; A[cc+6][ol] = v1.z; A[cc+7][ol] = v1.w;
    }
    {
      int jl = t >> 2, q = t & 3;
      const float* src = &E[((size_t)b * 1024 + j0 + jl) * 768 + kc + q * 8];
      float4 v0 = *(const float4*)src, v1 = *(const float4*)(src + 4);
      int cc = q * 8;
      Bs[cc+0][jl] = v0.x; Bs[cc+1][jl] = v0.y; Bs[cc+2][jl] = v0.z; Bs[cc+3][jl] = v0.w;
      Bs[cc+4][jl] = v1.x; Bs[cc+5][jl] = v1.y; Bs[cc+6][jl] = v1.z; Bs[cc+7][jl] = v1.w;
    }
    __syncthreads();
#pragma unroll 4
    for (int k = 0; k < 32; k++) {
      float4 a = *(const float4*)&A[k][to * 4];
      float4 bv = *(const float4*)&Bs[k][tj * 4];
      float av[4] = {a.x, a.y, a.z, a.w};
      float bb[4] = {bv.x, bv.y, bv.z, bv.w};
#pragma unroll
      for (int i = 0; i < 4; i++)
#pragma unroll
        for (int j = 0; j < 4; j++)
          acc[i][j] = fmaf(av[i], bb[j], acc[i][j]);
    }
    __syncthreads();
  }
#pragma unroll
  for (int i = 0; i < 4; i++) {
    int o = o0 + to * 4 + i;
    float gg = g[o], bb = cb[o], bo = bt[o];
    float4 v;
    float x0 = fmaf(gg, acc[i][0] + bb, bo); v.x = x0 > 0.0f ? x0 : 0.0f;
    float x1 = fmaf(gg, acc[i][1] + bb, bo); v.y = x1 > 0.0f ? x1 : 0.0f;
    float x2 = fmaf(gg, acc[i][2] + bb, bo); v.z = x2 > 0.0f ? x2 : 0.0f;
    float x3 = fmaf(gg, acc[i][3] + bb, bo); v.w = x3 > 0.0f ? x3 : 0.0f;
    *(float4*)&out1[((size_t)b * 256 + o) * 1024 + j0 + tj * 4] = v;
  }
}

extern "C" void kernel_launch(void* const* d_in, const int* in_sizes, int n_in,
                              void* d_out, int out_size, void* d_ws, size_t ws_size,
                              hipStream_t stream) {
  (void)in_sizes; (void)n_in; (void)out_size; (void)ws_size;
  const float* sf    = (const float*)d_in[0];
  const float* df    = (const float*)d_in[1];
  const float* coor  = (const float*)d_in[2];
  const float* d2sw  = (const float*)d_in[3];
  const float* d2sb  = (const float*)d_in[4];
  const float* d2sg  = (const float*)d_in[5];
  const float* d2sbt = (const float*)d_in[6];
  const float* spW   = (const float*)d_in[7];
  const float* spb   = (const float*)d_in[8];
  const float* spg   = (const float*)d_in[9];
  const float* spbt  = (const float*)d_in[10];
  const float* dnW   = (const float*)d_in[11];
  const float* dnb   = (const float*)d_in[12];
  const float* dng   = (const float*)d_in[13];
  const float* dnbt  = (const float*)d_in[14];
  const float* dsw   = (const float*)d_in[15];
  const float* dsb   = (const float*)d_in[16];
  const float* dsg   = (const float*)d_in[17];
  const float* dsbt  = (const float*)d_in[18];

  float* ws   = (float*)d_ws;
  float* XT   = ws + OFF_XT;
  float* P    = ws + OFF_P;
  float* Q    = ws + OFF_Q;
  float* SQD  = ws + OFF_SQD;
  float* SPFD = ws + OFF_SPFD;
  float* XS   = ws + OFF_XS;
  float* PS   = ws + OFF_PS;
  float* QS   = ws + OFF_QS;
  float* SUP  = ws + OFF_SUP;
  float* PDL  = ws + OFF_PDL;
  int*   PIL  = (int*)(ws + OFF_PIL);
  int*   KNN  = (int*)(ws + OFF_KNN);
  int*   IDXS = (int*)(ws + OFF_IDXS);
  int*   FPS  = (int*)(ws + OFF_FPS);
  float* SD   = ws + OFF_SD;
  float* E    = XT;  // alias: XT dead after k_pq

  float* out0 = (float*)d_out;
  float* out1 = out0 + 16384;
  float* out2 = out1 + 1048576;

  hipMemsetAsync(SPFD, 0, 16384 * sizeof(float), stream);

  k_sqd128<<<dim3(4, 16), 256, 0, stream>>>(df, SQD);
  k_sd<<<dim3(4), 256, 0, stream>>>(sf, SD);
  k_build_xt_dense<<<dim3(4, 64, 4), 256, 0, stream>>>(df, XT);
  k_build_xt_sparse<<<dim3(2048), 256, 0, stream>>>(sf, XT);
  k_d2s<<<dim3(4, 2, 64), 256, 0, stream>>>(df, d2sw, d2sb, d2sg, d2sbt, SPFD);
  k_fps<<<dim3(4), 128, 0, stream>>>(coor, FPS, out2);
  k_sparse_graph<<<dim3(4), 256, 0, stream>>>(sf, SPFD, XS, IDXS);
  k_sparse_pq<<<dim3(128), 256, 0, stream>>>(XS, spW, PS, QS);
  k_sparse_combine<<<dim3(128), 256, 0, stream>>>(PS, QS, IDXS, spg, spb, spbt, SUP);
  k_gather_out0<<<dim3(4), 256, 0, stream>>>(SUP, FPS, out0);
  k_knn<<<dim3(2, 64, 4), 256, 0, stream>>>(df, SQD, SD, PDL, PIL);
  k_knn_merge<<<dim3(64), 256, 0, stream>>>(PDL, PIL, KNN);
  k_pq<<<dim3(64, 4, 4), 256, 0, stream>>>(XT, dnW, P, Q);
  k_build_E<<<dim3(64, 16, 4), 256, 0, stream>>>(P, Q, KNN, FPS, dng, dnb, dnbt, E);
  k_ds_gemm<<<dim3(16, 4, 4), 256, 0, stream>>>(dsw, E, dsb, dsg, dsbt, out1);
}

// Round 3
// 702.891 us; speedup vs baseline: 2.0449x; 1.9813x over previous
//
#include <hip/hip_runtime.h>

#define NPNT 4096
#define NSTK 32

typedef _Float16 half8 __attribute__((ext_vector_type(8)));
typedef float f32x4 __attribute__((ext_vector_type(4)));

// ---------------- workspace layout (floats) ----------------
static const size_t OFF_XT   = 0;          // 4*4096*256 = 4194304 (aliased by E later)
static const size_t OFF_P    = 4194304;    // 4194304 (XH/XL alias this region before k_pq runs)
static const size_t OFF_Q    = 8388608;    // 4194304
static const size_t OFF_SQD  = 12582912;   // 16384
static const size_t OFF_SPFD = 12599296;   // 16384
static const size_t OFF_XS   = 12615680;   // 32768
static const size_t OFF_PS   = 12648448;   // 32768
static const size_t OFF_QS   = 12681216;   // 32768
static const size_t OFF_SUP  = 12713984;   // 32768
static const size_t OFF_PDL  = 12746752;   // 327680
static const size_t OFF_PIL  = 13074432;   // 327680 (int)
static const size_t OFF_KNN  = 13402112;   // 163840 (int)
static const size_t OFF_IDXS = 13565952;   // 256 (int)
static const size_t OFF_FPS  = 13566208;   // 64 (int)
static const size_t OFF_SD   = 13566272;   // 4096 (stroke-pair dists, 4*32*32)

__device__ __forceinline__ bool lexlt(float d1, int i1, float d2, int i2) {
  return (d1 < d2) || (d1 == d2 && i1 < i2);
}
__device__ __forceinline__ void insert10(float ld[10], int li[10], float d, int i) {
  if (!lexlt(d, i, ld[9], li[9])) return;
  ld[9] = d; li[9] = i;
#pragma unroll
  for (int j = 9; j > 0; j--) {
    if (lexlt(ld[j], li[j], ld[j-1], li[j-1])) {
      float td = ld[j]; ld[j] = ld[j-1]; ld[j-1] = td;
      int ti = li[j]; li[j] = li[j-1]; li[j-1] = ti;
    }
  }
}

// ---------------- K0a: Xt dense half (transpose dense_fea [b,c,n] -> Xt[b,n,c]) ----------------
__global__ __launch_bounds__(256) void k_build_xt_dense(const float* __restrict__ df, float* __restrict__ xt) {
  int b = blockIdx.x, n0 = blockIdx.y * 64, c0 = blockIdx.z * 32;
  __shared__ float T[32][68];
  int t = threadIdx.x;
  {
    int cl = t >> 3, seg = t & 7;
#pragma unroll
    for (int r = 0; r < 2; r++) {
      int f4 = seg * 2 + r;
      float4 v = *(const float4*)&df[((size_t)b * 128 + c0 + cl) * NPNT + n0 + f4 * 4];
      *(float4*)&T[cl][f4 * 4] = v;
    }
  }
  __syncthreads();
  {
    int nl = t >> 2, q = t & 3;
    float4 v0, v1;
    v0.x = T[q*8+0][nl]; v0.y = T[q*8+1][nl]; v0.z = T[q*8+2][nl]; v0.w = T[q*8+3][nl];
    v1.x = T[q*8+4][nl]; v1.y = T[q*8+5][nl]; v1.z = T[q*8+6][nl]; v1.w = T[q*8+7][nl];
    float* dst = &xt[((size_t)b * NPNT + n0 + nl) * 256 + c0 + q * 8];
    *(float4*)dst = v0; *(float4*)(dst + 4) = v1;
  }
}

// ---------------- K0b: Xt sparse half ----------------
__global__ __launch_bounds__(256) void k_build_xt_sparse(const float* __restrict__ sf, float* __restrict__ xt) {
  int tid = blockIdx.x * 256 + threadIdx.x;
  int b = tid >> 17;
  int rem = tid & 131071;
  int n = rem >> 5, q = rem & 31;
  int s = n >> 7;
  float4 v;
  v.x = sf[((size_t)b * 128 + q*4+0) * NSTK + s];
  v.y = sf[((size_t)b * 128 + q*4+1) * NSTK + s];
  v.z = sf[((size_t)b * 128 + q*4+2) * NSTK + s];
  v.w = sf[((size_t)b * 128 + q*4+3) * NSTK + s];
  *(float4*)&xt[((size_t)b * NPNT + n) * 256 + 128 + q * 4] = v;
}

// ---------------- K0c: sqd[b*4096+n] = sum over DENSE 128 ch of df^2 ----------------
__global__ __launch_bounds__(256) void k_sqd128(const float* __restrict__ df, float* __restrict__ sqd) {
  int b = blockIdx.x, n0 = blockIdx.y * 256;
  int n = n0 + threadIdx.x;
  float acc = 0.0f;
#pragma unroll 4
  for (int c = 0; c < 128; c++) {
    float v = df[((size_t)b * 128 + c) * NPNT + n];
    acc = fmaf(v, v, acc);
  }
  sqd[(size_t)b * NPNT + n] = acc;
}

// ---------------- K0d: SD[b][s][u] = ||sf[:,s] - sf[:,u]||^2 ----------------
__global__ __launch_bounds__(256) void k_sd(const float* __restrict__ sf, float* __restrict__ SD) {
  int b = blockIdx.x, t = threadIdx.x;
  __shared__ float X[32][132];
  for (int idx = t; idx < 128 * 32; idx += 256) {
    int c = idx >> 5, s = idx & 31;
    X[s][c] = sf[((size_t)b * 128 + c) * NSTK + s];
  }
  __syncthreads();
#pragma unroll
  for (int rep = 0; rep < 4; rep++) {
    int p = t + rep * 256;
    int s = p >> 5, u = p & 31;
    float acc = 0.0f;
    for (int c = 0; c < 128; c++) {
      float d = X[s][c] - X[u][c];
      acc = fmaf(d, d, acc);
    }
    SD[(size_t)b * 1024 + p] = acc;
  }
}

// ---------------- K0e: split df into f16 hi/lo, point-major XH/XL [b][n][128] ----------------
__global__ __launch_bounds__(256) void k_split(const float* __restrict__ df,
    _Float16* __restrict__ XH, _Float16* __restrict__ XL) {
  // grid (4, 64): b, ntile(64)
  int b = blockIdx.x, n0 = blockIdx.y * 64;
  int t = threadIdx.x;
  __shared__ float T[128][68];
  {
    int c = t >> 1, nh = (t & 1) * 32;
    const float* src = &df[((size_t)b * 128 + c) * NPNT + n0 + nh];
#pragma unroll
    for (int j = 0; j < 8; j++) {
      float4 v = *(const float4*)&src[j * 4];
      *(float4*)&T[c][nh + j * 4] = v;
    }
  }
  __syncthreads();
  {
    int n = t >> 2, cseg = (t & 3) * 32;
    size_t base = ((size_t)b * NPNT + n0 + n) * 128 + cseg;
#pragma unroll
    for (int k = 0; k < 4; k++) {
      half8 hv, lv;
#pragma unroll
      for (int e = 0; e < 8; e++) {
        float x = T[cseg + k * 8 + e][n];
        _Float16 hi = (_Float16)x;
        float hf = (float)hi;
        _Float16 lo = (_Float16)(x - hf);
        hv[e] = hi; lv[e] = lo;
      }
      *(half8*)&XH[base + k * 8] = hv;
      *(half8*)&XL[base + k * 8] = lv;
    }
  }
}

// ---------------- K1: DenseToSparse conv(1,3)+BN+ReLU+max over points ----------------
__global__ __launch_bounds__(256) void k_d2s(const float* __restrict__ df, const float* __restrict__ w,
    const float* __restrict__ cb, const float* __restrict__ g, const float* __restrict__ bt,
    float* __restrict__ spfd) {
  int b = blockIdx.x, o0 = blockIdx.y * 64, n0 = blockIdx.z * 64;
  int t = threadIdx.x;
  __shared__ float A[96][64];
  __shared__ float Bs[32][68];
  float acc[4][4];
#pragma unroll
  for (int i = 0; i < 4; i++)
#pragma unroll
    for (int j = 0; j < 4; j++) acc[i][j] = 0.0f;
  int tn = t & 15, to = t >> 4;
  for (int ic = 0; ic < 128; ic += 32) {
    {
      int ol = t >> 2, q = t & 3;
      const float* src = &w[((size_t)(o0 + ol) * 128 + ic) * 3 + q * 24];
#pragma unroll
      for (int r = 0; r < 6; r++) {
        float4 v = *(const float4*)&src[r * 4];
        int e = q * 24 + r * 4;
        A[e+0][ol] = v.x; A[e+1][ol] = v.y; A[e+2][ol] = v.z; A[e+3][ol] = v.w;
      }
    }
    for (int idx = t; idx < 32 * 17; idx += 256) {
      int row = idx / 17, f4 = idx % 17;
      int nb = n0 + f4 * 4;
      const float* srow = &df[((size_t)b * 128 + ic + row) * NPNT];
      float4 v;
      if (nb + 3 < NPNT) v = *(const float4*)&srow[nb];
      else {
        v.x = srow[nb   < NPNT ? nb   : NPNT-1];
        v.y = srow[nb+1 < NPNT ? nb+1 : NPNT-1];
        v.z = srow[nb+2 < NPNT ? nb+2 : NPNT-1];
        v.w = srow[nb+3 < NPNT ? nb+3 : NPNT-1];
      }
      *(float4*)&Bs[row][f4 * 4] = v;
    }
    __syncthreads();
#pragma unroll 2
    for (int ii = 0; ii < 32; ii++) {
      float bv[8];
      *(float4*)&bv[0] = *(const float4*)&Bs[ii][tn * 4];
      *(float4*)&bv[4] = *(const float4*)&Bs[ii][tn * 4 + 4];
#pragma unroll
      for (int kw = 0; kw < 3; kw++) {
        float4 av = *(const float4*)&A[ii * 3 + kw][to * 4];
#pragma unroll
        for (int j = 0; j < 4; j++) {
          float bvj = bv[kw + j];
          acc[0][j] = fmaf(av.x, bvj, acc[0][j]);
          acc[1][j] = fmaf(av.y, bvj, acc[1][j]);
          acc[2][j] = fmaf(av.z, bvj, acc[2][j]);
          acc[3][j] = fmaf(av.w, bvj, acc[3][j]);
        }
      }
    }
    __syncthreads();
  }
  int s = n0 >> 7;
#pragma unroll
  for (int i = 0; i < 4; i++) {
    int o = o0 + to * 4 + i;
    float gg = g[o], bb = cb[o], bo = bt[o];
    float m = 0.0f;
#pragma unroll
    for (int j = 0; j < 4; j++) {
      int n = n0 + tn * 4 + j;
      int p = n & 127;
      if (p < 126) {
        float v = fmaf(gg, acc[i][j] + bb, bo);
        v = v > 0.0f ? v : 0.0f;
        m = v > m ? v : m;
      }
    }
    atomicMax((int*)&spfd[((size_t)b * 128 + o) * NSTK + s], __float_as_int(m));
  }
}

// ---------------- K2: FPS + out2 gather ----------------
__global__ __launch_bounds__(128) void k_fps(const float* __restrict__ coor, int* __restrict__ fpsidx,
                                             float* __restrict__ out2) {
  int b = blockIdx.x, t = threadIdx.x;
  __shared__ float X[32][132];
  __shared__ float dist[32];
  __shared__ int far_s;
  __shared__ int sel[16];
  for (int idx = t; idx < 32 * 32; idx += 128) {
    int r = idx >> 5, q = idx & 31;
    *(float4*)&X[r][q * 4] = *(const float4*)&coor[((size_t)b * 32 + r) * 128 + q * 4];
  }
  if (t < 32) dist[t] = 1e10f;
  if (t == 0) far_s = 0;
  __syncthreads();
  for (int it = 0; it < 16; it++) {
    int far = far_s;
    if (t == 0) sel[it] = far;
    if (t < 32) {
      float d = 0.0f;
      for (int c = 0; c < 128; c++) { float dd = X[t][c] - X[far][c]; d = fmaf(dd, dd, d); }
      float dm = dist[t];
      dist[t] = d < dm ? d : dm;
    }
    __syncthreads();
    if (t == 0) {
      float best = -1.0f; int bi = 0;
      for (int m = 0; m < 32; m++) if (dist[m] > best) { best = dist[m]; bi = m; }
      far_s = bi;
    }
    __syncthreads();
  }
  if (t < 16) fpsidx[b * 16 + t] = sel[t];
  __syncthreads();
  for (int idx = t; idx < 16 * 32; idx += 128) {
    int j = idx >> 5, q = idx & 31;
    *(float4*)&out2[((size_t)b * 16 + j) * 128 + q * 4] = *(const float4*)&X[sel[j]][q * 4];
  }
}

// ---------------- K3a: sparse graph ----------------
__global__ __launch_bounds__(256) void k_sparse_graph(const float* __restrict__ sf, const float* __restrict__ spfd,
    float* __restrict__ xs, int* __restrict__ idxs) {
  int b = blockIdx.x, t = threadIdx.x;
  __shared__ float X[32][260];
  __shared__ float sq[32];
  __shared__ float D[32][33];
  for (int idx = t; idx < 32 * 256; idx += 256) {
    int n = idx >> 8, c = idx & 255;
    float v = (c < 128) ? sf[((size_t)b * 128 + c) * NSTK + n]
                        : spfd[((size_t)b * 128 + (c - 128)) * NSTK + n];
    X[n][c] = v;
  }
  __syncthreads();
  for (int idx = t; idx < 32 * 64; idx += 256) {
    int n = idx >> 6, q = idx & 63;
    *(float4*)&xs[((size_t)b * 32 + n) * 256 + q * 4] = *(const float4*)&X[n][q * 4];
  }
  if (t < 32) {
    float s = 0.0f;
    for (int c = 0; c < 256; c++) s = fmaf(X[t][c], X[t][c], s);
    sq[t] = s;
  }
  __syncthreads();
  {
    int n = t >> 3;
    for (int mg = 0; mg < 4; mg++) {
      int m = (t & 7) + mg * 8;
      float dot = 0.0f;
      for (int c = 0; c < 256; c++) dot = fmaf(X[n][c], X[m][c], dot);
      D[n][m] = (sq[n] - 2.0f * dot) + sq[m];
    }
  }
  __syncthreads();
  if (t < 32) {
    float d0 = 1e30f, d1 = 1e30f; int i0 = 0, i1 = 0;
    for (int m = 0; m < 32; m++) {
      float d = D[t][m];
      if (d < d0) { d1 = d0; i1 = i0; d0 = d; i0 = m; }
      else if (d < d1) { d1 = d; i1 = m; }
    }
    idxs[(b * 32 + t) * 2 + 0] = i0;
    idxs[(b * 32 + t) * 2 + 1] = i1;
  }
}

// ---------------- K3b: sparse P/Q ----------------
__global__ __launch_bounds__(256) void k_sparse_pq(const float* __restrict__ xs, const float* __restrict__ W,
    float* __restrict__ Ps, float* __restrict__ Qs) {
  int b = blockIdx.x >> 5, n = blockIdx.x & 31;
  int o = threadIdx.x;
  const float* xr = &xs[((size_t)b * 32 + n) * 256];
  float accP = 0.0f, accQ = 0.0f;
  for (int c = 0; c < 256; c++) {
    float xc = xr[c];
    float w1 = W[(size_t)c * 256 + o];
    float w2 = W[(size_t)(c + 256) * 256 + o];
    accP = fmaf(xc, w1 - w2, accP);
    accQ = fmaf(xc, w2, accQ);
  }
  Ps[((size_t)b * 32 + n) * 256 + o] = accP;
  Qs[((size_t)b * 32 + n) * 256 + o] = accQ;
}

// ---------------- K3c: sparse combine ----------------
__global__ __launch_bounds__(256) void k_sparse_combine(const float* __restrict__ Ps, const float* __restrict__ Qs,
    const int* __restrict__ idxs, const float* __restrict__ g, const float* __restrict__ cb,
    const float* __restrict__ bt, float* __restrict__ sup) {
  int b = blockIdx.x >> 5, n = blockIdx.x & 31, o = threadIdx.x;
  int i0 = idxs[(b * 32 + n) * 2 + 0], i1 = idxs[(b * 32 + n) * 2 + 1];
  float p = Ps[((size_t)b * 32 + n) * 256 + o];
  float q0 = Qs[((size_t)b * 32 + i0) * 256 + o];
  float q1 = Qs[((size_t)b * 32 + i1) * 256 + o];
  float gg = g[o], bb = cb[o], bo = bt[o];
  float h0 = fmaf(gg, p + q0 + bb, bo); h0 = h0 > 0.0f ? h0 : 0.0f;
  float h1 = fmaf(gg, p + q1 + bb, bo); h1 = h1 > 0.0f ? h1 : 0.0f;
  sup[((size_t)b * 32 + n) * 256 + o] = h0 > h1 ? h0 : h1;
}

// ---------------- K8: gather out0 ----------------
__global__ __launch_bounds__(256) void k_gather_out0(const float* __restrict__ sup, const int* __restrict__ fps,
                                                     float* __restrict__ out0) {
  int b = blockIdx.x, o = threadIdx.x;
  for (int j = 0; j < 16; j++) {
    int n = fps[b * 16 + j];
    out0[((size_t)b * 256 + o) * 16 + j] = sup[((size_t)b * 32 + n) * 256 + o];
  }
}

// ---------------- K4: dense kNN via f16 hi/lo split MFMA + tau-guarded top-10 ----------------
// grid (2, 64, 4): m-half, rowblock(64 rows = 4 waves x 16 rows), b. 256 threads.
// Waves fully independent: no __syncthreads anywhere.
__global__ __launch_bounds__(256, 2) void k_knn_mfma(const _Float16* __restrict__ XH,
    const _Float16* __restrict__ XL, const float* __restrict__ sqd, const float* __restrict__ SD,
    float* __restrict__ pd, int* __restrict__ pi) {
  const int h = blockIdx.x, rb = blockIdx.y, b = blockIdx.z;
  const int t = threadIdx.x;
  const int w = t >> 6, L = t & 63;
  const int c15 = L & 15, q = L >> 4;
  const int n0w = rb * 64 + w * 16;
  const int s_stk = (rb * 64) >> 7;
  const size_t bofs = (size_t)b * NPNT;

  __shared__ float Dw[4][16][132];
  __shared__ float tauW[4][16][4];

  // A fragments (16 rows x 128 K, hi+lo), register-resident for the whole sweep.
  // MFMA 16x16x32 f16 A-layout: lane holds A[m=lane&15][k = (lane>>4)*8 + j].
  half8 ah[4], al[4];
  {
    const _Float16* ap  = XH + (bofs + n0w + c15) * 128 + q * 8;
    const _Float16* apl = XL + (bofs + n0w + c15) * 128 + q * 8;
#pragma unroll
    for (int ch = 0; ch < 4; ch++) {
      ah[ch] = *(const half8*)(ap + ch * 32);
      al[ch] = *(const half8*)(apl + ch * 32);
    }
  }
  float snr[4];
#pragma unroll
  for (int r = 0; r < 4; r++) snr[r] = sqd[bofs + n0w + q * 4 + r];

  float ld[10]; int li[10];
#pragma unroll
  for (int j = 0; j < 10; j++) { ld[j] = 1e30f; li[j] = 0x7fffffff; }

  const bool own_here = ((s_stk >> 4) == h);
  const int r_sel = L >> 2, sl = L & 3;
  float tauR = 1e30f;

  for (int it = 0; it < 16; it++) {
    int u;
    if (own_here) {
      if (it == 0) u = s_stk;
      else { u = h * 16 + it - 1; if (u >= s_stk) u++; }
    } else u = h * 16 + it;
    const int m0 = u * 128;
    const float SDv = SD[((size_t)b * 32 + s_stk) * 32 + u];
    float smv[8];
#pragma unroll
    for (int cg = 0; cg < 8; cg++) smv[cg] = sqd[bofs + m0 + cg * 16 + c15];

    f32x4 zz = {0.0f, 0.0f, 0.0f, 0.0f};
    f32x4 acc[8];
#pragma unroll
    for (int cg = 0; cg < 8; cg++) acc[cg] = zz;

    const _Float16* bbase  = XH + (bofs + m0) * 128 + q * 8;
    const _Float16* bbasel = XL + (bofs + m0) * 128 + q * 8;
#pragma unroll
    for (int ch = 0; ch < 4; ch++) {
#pragma unroll
      for (int cg = 0; cg < 8; cg++) {
        const _Float16* bp  = bbase  + (size_t)(cg * 16 + c15) * 128 + ch * 32;
        const _Float16* bpl = bbasel + (size_t)(cg * 16 + c15) * 128 + ch * 32;
        half8 bh = *(const half8*)bp;
        half8 bl = *(const half8*)bpl;
        acc[cg] = __builtin_amdgcn_mfma_f32_16x16x32_f16(ah[ch], bh, acc[cg], 0, 0, 0);
        acc[cg] = __builtin_amdgcn_mfma_f32_16x16x32_f16(ah[ch], bl, acc[cg], 0, 0, 0);
        acc[cg] = __builtin_amdgcn_mfma_f32_16x16x32_f16(al[ch], bh, acc[cg], 0, 0, 0);
      }
    }

    // epilogue: C/D layout row=(lane>>4)*4+r, col=lane&15 -> distances to Dw
#pragma unroll
    for (int cg = 0; cg < 8; cg++) {
      float basec = SDv + smv[cg];
#pragma unroll
      for (int r = 0; r < 4; r++) {
        float d = snr[r] + basec - 2.0f * acc[cg][r];
        Dw[w][q * 4 + r][cg * 16 + c15] = d;
      }
    }
    // selection: 4 lanes per row, 32-col slices (wave-local LDS, lgkmcnt-ordered)
    if (it == 0) {
#pragma unroll
      for (int jj = 0; jj < 8; jj++) {
        float4 dv = *(const float4*)&Dw[w][r_sel][sl * 32 + jj * 4];
        int ib = m0 + sl * 32 + jj * 4;
        insert10(ld, li, dv.x, ib + 0);
        insert10(ld, li, dv.y, ib + 1);
        insert10(ld, li, dv.z, ib + 2);
        insert10(ld, li, dv.w, ib + 3);
      }
    } else {
#pragma unroll
      for (int jj = 0; jj < 8; jj++) {
        float4 dv = *(const float4*)&Dw[w][r_sel][sl * 32 + jj * 4];
        int ib = m0 + sl * 32 + jj * 4;
        if (dv.x <= tauR) insert10(ld, li, dv.x, ib + 0);
        if (dv.y <= tauR) insert10(ld, li, dv.y, ib + 1);
        if (dv.z <= tauR) insert10(ld, li, dv.z, ib + 2);
        if (dv.w <= tauR) insert10(ld, li, dv.w, ib + 3);
      }
    }
    // per-row conservative tau = min over the 4 slices' 10th-best
    tauW[w][r_sel][sl] = ld[9];
    float4 tv = *(const float4*)&tauW[w][r_sel][0];
    tauR = fminf(fminf(tv.x, tv.y), fminf(tv.z, tv.w));
  }

  // merge the 4 per-slice lists of each row (wave-local)
#pragma unroll
  for (int j = 0; j < 10; j++) {
    Dw[w][r_sel][sl * 10 + j] = ld[j];
    Dw[w][r_sel][40 + sl * 10 + j] = __int_as_float(li[j]);
  }
  if (L < 16) {
    float fd[10]; int fi[10];
#pragma unroll
    for (int j = 0; j < 10; j++) { fd[j] = 1e30f; fi[j] = 0x7fffffff; }
    for (int x = 0; x < 40; x++)
      insert10(fd, fi, Dw[w][L][x], __float_as_int(Dw[w][L][40 + x]));
    size_t row = bofs + n0w + L;
#pragma unroll
    for (int j = 0; j < 10; j++) {
      pd[(row * 2 + h) * 10 + j] = fd[j];
      pi[(row * 2 + h) * 10 + j] = fi[j];
    }
  }
}

// ---------------- K4b: merge the 2 half-lists ----------------
__global__ __launch_bounds__(256) void k_knn_merge(const float* __restrict__ pd, const int* __restrict__ pi,
                                                   int* __restrict__ knn) {
  int row = blockIdx.x * 256 + threadIdx.x;
  if (row >= 4 * NPNT) return;
  float ld[10]; int li[10];
#pragma unroll
  for (int j = 0; j < 10; j++) { ld[j] = pd[(size_t)row * 20 + j]; li[j] = pi[(size_t)row * 20 + j]; }
#pragma unroll
  for (int j = 0; j < 10; j++) insert10(ld, li, pd[(size_t)row * 20 + 10 + j], pi[(size_t)row * 20 + 10 + j]);
#pragma unroll
  for (int j = 0; j < 10; j++) knn[(size_t)row * 10 + j] = li[j];
}

// ---------------- K5: dense P/Q GEMMs ----------------
__global__ __launch_bounds__(256) void k_pq(const float* __restrict__ xt, const float* __restrict__ W,
    float* __restrict__ P, float* __restrict__ Q) {
  int n0 = blockIdx.x * 64, o0 = blockIdx.y * 64, b = blockIdx.z;
  int t = threadIdx.x;
  __shared__ float A[32][68];
  __shared__ float B1[32][64], B2[32][64];
  float accP[4][4], accQ[4][4];
#pragma unroll
  for (int i = 0; i < 4; i++)
#pragma unroll
    for (int j = 0; j < 4; j++) { accP[i][j] = 0.0f; accQ[i][j] = 0.0f; }
  int tn = t & 15, to = t >> 4;
  for (int kc = 0; kc < 256; kc += 32) {
    {
      int nl = t >> 2, c4 = t & 3;
      const float* src = &xt[((size_t)b * NPNT + n0 + nl) * 256 + kc + c4 * 8];
      float4 v0 = *(const float4*)src;
      float4 v1 = *(const float4*)(src + 4);
      int cc = c4 * 8;
      A[cc+0][nl] = v0.x; A[cc+1][nl] = v0.y; A[cc+2][nl] = v0.z; A[cc+3][nl] = v0.w;
      A[cc+4][nl] = v1.x; A[cc+5][nl] = v1.y; A[cc+6][nl] = v1.z; A[cc+7][nl] = v1.w;
    }
    {
      int kl = t >> 3, qq = t & 7;
      const float* s1 = &W[(size_t)(kc + kl) * 256 + o0 + qq * 8];
      const float* s2 = &W[(size_t)(kc + kl + 256) * 256 + o0 + qq * 8];
      float4 a0 = *(const float4*)s1, a1 = *(const float4*)(s1 + 4);
      float4 b0 = *(const float4*)s2, b1 = *(const float4*)(s2 + 4);
      *(float4*)&B2[kl][qq * 8] = b0; *(float4*)&B2[kl][qq * 8 + 4] = b1;
      float4 d0, d1;
      d0.x = a0.x - b0.x; d0.y = a0.y - b0.y; d0.z = a0.z - b0.z; d0.w = a0.w - b0.w;
      d1.x = a1.x - b1.x; d1.y = a1.y - b1.y; d1.z = a1.z - b1.z; d1.w = a1.w - b1.w;
      *(float4*)&B1[kl][qq * 8] = d0; *(float4*)&B1[kl][qq * 8 + 4] = d1;
    }
    __syncthreads();
#pragma unroll 4
    for (int k = 0; k < 32; k++) {
      float4 a  = *(const float4*)&A[k][tn * 4];
      float4 w1 = *(const float4*)&B1[k][to * 4];
      float4 w2 = *(const float4*)&B2[k][to * 4];
      float av[4] = {a.x, a.y, a.z, a.w};
      float w1v[4] = {w1.x, w1.y, w1.z, w1.w};
      float w2v[4] = {w2.x, w2.y, w2.z, w2.w};
#pragma unroll
      for (int i = 0; i < 4; i++)
#pragma unroll
        for (int j = 0; j < 4; j++) {
          accP[i][j] = fmaf(av[i], w1v[j], accP[i][j]);
          accQ[i][j] = fmaf(av[i], w2v[j], accQ[i][j]);
        }
    }
    __syncthreads();
  }
#pragma unroll
  for (int i = 0; i < 4; i++) {
    size_t base = ((size_t)b * NPNT + n0 + tn * 4 + i) * 256 + o0 + to * 4;
    float4 vp, vq;
    vp.x = accP[i][0]; vp.y = accP[i][1]; vp.z = accP[i][2]; vp.w = accP[i][3];
    vq.x = accQ[i][0]; vq.y = accQ[i][1]; vq.z = accQ[i][2]; vq.w = accQ[i][3];
    *(float4*)&P[base] = vp;
    *(float4*)&Q[base] = vq;
  }
}

// ---------------- K6: build im2col E ----------------
__global__ __launch_bounds__(256) void k_build_E(const float* __restrict__ P, const float* __restrict__ Q,
    const int* __restrict__ knn, const int* __restrict__ fps,
    const float* __restrict__ g, const float* __restrict__ cb, const float* __restrict__ bt,
    float* __restrict__ E) {
  int pp = blockIdx.x, j = blockIdx.y, b = blockIdx.z;
  int t = threadIdx.x;
  int s = fps[b * 16 + j];
  float gg = g[t], bb = cb[t], bo = bt[t];
  float v[3];
#pragma unroll
  for (int dp = 0; dp < 3; dp++) {
    int p = 2 * pp - 1 + dp;
    float val = 0.0f;
    if (p >= 0 && p < 128) {
      int n = s * 128 + p;
      float pv = P[((size_t)b * NPNT + n) * 256 + t] + bb;
      const int* id = &knn[((size_t)b * NPNT + n) * 10];
      float mx = 0.0f;
#pragma unroll
      for (int k = 0; k < 10; k++) {
        float qv = Q[((size_t)b * NPNT + id[k]) * 256 + t];
        float h = fmaf(gg, pv + qv, bo);
        mx = h > mx ? h : mx;
      }
      val = mx;
    }
    v[dp] = val;
  }
  size_t base = ((size_t)(b * 16 + j) * 64 + pp) * 768;
  E[base + 3 * t + 0] = v[0];
  E[base + 3 * t + 1] = v[1];
  E[base + 3 * t + 2] = v[2];
}

// ---------------- K7: downsample GEMM ----------------
__global__ __launch_bounds__(256) void k_ds_gemm(const float* __restrict__ Wd, const float* __restrict__ E,
    const float* __restrict__ cb, const float* __restrict__ g, const float* __restrict__ bt,
    float* __restrict__ out1) {
  int j0 = blockIdx.x * 64, o0 = blockIdx.y * 64, b = blockIdx.z;
  int t = threadIdx.x;
  __shared__ float A[32][68];
  __shared__ float Bs[32][68];
  float acc[4][4];
#pragma unroll
  for (int i = 0; i < 4; i++)
#pragma unroll
    for (int j = 0; j < 4; j++) acc[i][j] = 0.0f;
  int tj = t & 15, to = t >> 4;
  for (int kc = 0; kc < 768; kc += 32) {
    {
      int ol = t >> 2, q = t & 3;
      const float* src = &Wd[(size_t)(o0 + ol) * 768 + kc + q * 8];
      float4 v0 = *(const float4*)src, v1 = *(const float4*)(src + 4);
      int cc = q * 8;
      A[cc+0][ol] = v0.x; A[cc+1][ol] = v0.y; A[cc+2][ol] = v0.z; A[cc+3][ol] = v0.w;
      A[cc+4][ol] = v1.x; A[cc+5][ol] = v1.y; A[cc+6][ol] = v1.z; A[cc+7][ol] = v1.w;
    }
    {
      int jl = t >> 2, q = t & 3;
      const float* src = &E[((size_t)b * 1024 + j0 + jl) * 768 + kc + q * 8];
      float4 v0 = *(const float4*)src, v1 = *(const float4*)(src + 4);
      int cc = q * 8;
      Bs[cc+0][jl] = v0.x; Bs[cc+1][jl] = v0.y; Bs[cc+2][jl] = v0.z; Bs[cc+3][jl] = v0.w;
      Bs[cc+4][jl] = v1.x; Bs[cc+5][jl] = v1.y; Bs[cc+6][jl] = v1.z; Bs[cc+7][jl] = v1.w;
    }
    __syncthreads();
#pragma unroll 4
    for (int k = 0; k < 32; k++) {
      float4 a = *(const float4*)&A[k][to * 4];
      float4 bv = *(const float4*)&Bs[k][tj * 4];
      float av[4] = {a.x, a.y, a.z, a.w};
      float bb[4] = {bv.x, bv.y, bv.z, bv.w};
#pragma unroll
      for (int i = 0; i < 4; i++)
#pragma unroll
        for (int j = 0; j < 4; j++)
          acc[i][j] = fmaf(av[i], bb[j], acc[i][j]);
    }
    __syncthreads();
  }
#pragma unroll
  for (int i = 0; i < 4; i++) {
    int o = o0 + to * 4 + i;
    float gg = g[o], bb = cb[o], bo = bt[o];
    float4 v;
    float x0 = fmaf(gg, acc[i][0] + bb, bo); v.x = x0 > 0.0f ? x0 : 0.0f;
    float x1 = fmaf(gg, acc[i][1] + bb, bo); v.y = x1 > 0.0f ? x1 : 0.0f;
    float x2 = fmaf(gg, acc[i][2] + bb, bo); v.z = x2 > 0.0f ? x2 : 0.0f;
    float x3 = fmaf(gg, acc[i][3] + bb, bo); v.w = x3 > 0.0f ? x3 : 0.0f;
    *(float4*)&out1[((size_t)b * 256 + o) * 1024 + j0 + tj * 4] = v;
  }
}

extern "C" void kernel_launch(void* const* d_in, const int* in_sizes, int n_in,
                              void* d_out, int out_size, void* d_ws, size_t ws_size,
                              hipStream_t stream) {
  (void)in_sizes; (void)n_in; (void)out_size; (void)ws_size;
  const float* sf    = (const float*)d_in[0];
  const float* df    = (const float*)d_in[1];
  const float* coor  = (const float*)d_in[2];
  const float* d2sw  = (const float*)d_in[3];
  const float* d2sb  = (const float*)d_in[4];
  const float* d2sg  = (const float*)d_in[5];
  const float* d2sbt = (const float*)d_in[6];
  const float* spW   = (const float*)d_in[7];
  const float* spb   = (const float*)d_in[8];
  const float* spg   = (const float*)d_in[9];
  const float* spbt  = (const float*)d_in[10];
  const float* dnW   = (const float*)d_in[11];
  const float* dnb   = (const float*)d_in[12];
  const float* dng   = (const float*)d_in[13];
  const float* dnbt  = (const float*)d_in[14];
  const float* dsw   = (const float*)d_in[15];
  const float* dsb   = (const float*)d_in[16];
  const float* dsg   = (const float*)d_in[17];
  const float* dsbt  = (const float*)d_in[18];

  float* ws   = (float*)d_ws;
  float* XT   = ws + OFF_XT;
  float* P    = ws + OFF_P;
  float* Q    = ws + OFF_Q;
  float* SQD  = ws + OFF_SQD;
  float* SPFD = ws + OFF_SPFD;
  float* XS   = ws + OFF_XS;
  float* PS   = ws + OFF_PS;
  float* QS   = ws + OFF_QS;
  float* SUP  = ws + OFF_SUP;
  float* PDL  = ws + OFF_PDL;
  int*   PIL  = (int*)(ws + OFF_PIL);
  int*   KNN  = (int*)(ws + OFF_KNN);
  int*   IDXS = (int*)(ws + OFF_IDXS);
  int*   FPS  = (int*)(ws + OFF_FPS);
  float* SD   = ws + OFF_SD;
  float* E    = XT;                         // alias: XT dead after k_pq
  _Float16* XH = (_Float16*)(ws + OFF_P);   // alias: P region free until k_pq
  _Float16* XL = XH + (size_t)4 * NPNT * 128;

  float* out0 = (float*)d_out;
  float* out1 = out0 + 16384;
  float* out2 = out1 + 1048576;

  hipMemsetAsync(SPFD, 0, 16384 * sizeof(float), stream);

  k_sqd128<<<dim3(4, 16), 256, 0, stream>>>(df, SQD);
  k_sd<<<dim3(4), 256, 0, stream>>>(sf, SD);
  k_split<<<dim3(4, 64), 256, 0, stream>>>(df, XH, XL);
  k_build_xt_dense<<<dim3(4, 64, 4), 256, 0, stream>>>(df, XT);
  k_build_xt_sparse<<<dim3(2048), 256, 0, stream>>>(sf, XT);
  k_d2s<<<dim3(4, 2, 64), 256, 0, stream>>>(df, d2sw, d2sb, d2sg, d2sbt, SPFD);
  k_fps<<<dim3(4), 128, 0, stream>>>(coor, FPS, out2);
  k_sparse_graph<<<dim3(4), 256, 0, stream>>>(sf, SPFD, XS, IDXS);
  k_sparse_pq<<<dim3(128), 256, 0, stream>>>(XS, spW, PS, QS);
  k_sparse_combine<<<dim3(128), 256, 0, stream>>>(PS, QS, IDXS, spg, spb, spbt, SUP);
  k_gather_out0<<<dim3(4), 256, 0, stream>>>(SUP, FPS, out0);
  k_knn_mfma<<<dim3(2, 64, 4), 256, 0, stream>>>(XH, XL, SQD, SD, PDL, PIL);
  k_knn_merge<<<dim3(64), 256, 0, stream>>>(PDL, PIL, KNN);
  k_pq<<<dim3(64, 4, 4), 256, 0, stream>>>(XT, dnW, P, Q);
  k_build_E<<<dim3(64, 16, 4), 256, 0, stream>>>(P, Q, KNN, FPS, dng, dnb, dnbt, E);
  k_ds_gemm<<<dim3(16, 4, 4), 256, 0, stream>>>(dsw, E, dsb, dsg, dsbt, out1);
}